// Round 2
// baseline (601.630 us; speedup 1.0000x reference)
//
#include <hip/hip_runtime.h>
#include <hip/hip_bf16.h>

#define BB 4
#define NN 2048
#define DD 128
#define HH 4
#define LOG2E 1.4426950408889634f
#define NEG_BIG (-1e30f)

typedef __attribute__((ext_vector_type(8))) short bf16x8;   // 8 bf16 in 4 VGPRs
typedef __attribute__((ext_vector_type(4))) float f32x4;    // MFMA accumulator

__device__ __forceinline__ unsigned short f2bf(float f) {
    union { float f; unsigned int u; } v; v.f = f;
    unsigned int r = v.u + 0x7FFF + ((v.u >> 16) & 1);      // round-nearest-even
    return (unsigned short)(r >> 16);
}

// ---------------------------------------------------------------------------
// Kernel A: wsv[h][i] = sum_o W[h,i,o]*a[h,o]; wdv likewise with a[h,D+o].
// ---------------------------------------------------------------------------
__global__ __launch_bounds__(128) void k_wvec(const float* __restrict__ W,
                                              const float* __restrict__ a,
                                              float* __restrict__ wsv,
                                              float* __restrict__ wdv) {
    int h = blockIdx.x;
    int i = threadIdx.x;
    const float* Wr  = W + (h * DD + i) * DD;
    const float* as_ = a + h * 2 * DD;
    const float* ad_ = as_ + DD;
    float s = 0.f, d = 0.f;
    for (int o = 0; o < DD; ++o) {
        float w = Wr[o];
        s += w * as_[o];
        d += w * ad_[o];
    }
    wsv[h * DD + i] = s;
    wdv[h * DD + i] = d;
}

// ---------------------------------------------------------------------------
// Kernel B: s[b,h,n] = x[b,n,:] . wsv[h]; d likewise. 64 rows/block.
// ---------------------------------------------------------------------------
__global__ __launch_bounds__(256) void k_sd(const float* __restrict__ x,
                                            const float* __restrict__ wsv,
                                            const float* __restrict__ wdv,
                                            float* __restrict__ s_out,
                                            float* __restrict__ d_out_) {
    __shared__ float xs[64 * 129];
    __shared__ float ws[4 * 129], wd[4 * 129];
    int tid = threadIdx.x;
    int b  = blockIdx.x / (NN / 64);
    int nb = (blockIdx.x % (NN / 64)) * 64;
    for (int idx = tid; idx < HH * DD; idx += 256) {
        ws[(idx >> 7) * 129 + (idx & 127)] = wsv[idx];
        wd[(idx >> 7) * 129 + (idx & 127)] = wdv[idx];
    }
    for (int idx = tid; idx < 64 * 128; idx += 256) {
        int r = idx >> 7, c = idx & 127;
        xs[r * 129 + c] = x[((size_t)b * NN + nb + r) * DD + c];
    }
    __syncthreads();
    int h = tid & 3, r = tid >> 2;
    float sv = 0.f, dv = 0.f;
#pragma unroll 8
    for (int i = 0; i < DD; ++i) {
        float xv = xs[r * 129 + i];
        sv += xv * ws[h * 129 + i];
        dv += xv * wd[h * 129 + i];
    }
    int n = nb + r;
    s_out[(b * HH + h) * NN + n] = sv;
    d_out_[(b * HH + h) * NN + n] = dv;
}

// ---------------------------------------------------------------------------
// Kernel H: h[b,h,n,o] = sum_i x[b,n,i]*W[h,i,o]; stored TRANSPOSED as bf16:
// hT[bh][o][n] (n contiguous) — the MFMA B-operand layout for k_attn_mfma.
// Inner loop vectorized: ds_read_b128 on xs (pad 132 keeps 16B align).
// ---------------------------------------------------------------------------
__global__ __launch_bounds__(256) void k_h(const float* __restrict__ x,
                                           const float* __restrict__ W,
                                           unsigned short* __restrict__ hT) {
    __shared__ float xs[32 * 132];
    int tid = threadIdx.x;
    int bh = blockIdx.x / (NN / 32);
    int nb = (blockIdx.x % (NN / 32)) * 32;
    int b = bh >> 2, h = bh & 3;
    for (int idx = tid; idx < 32 * 128; idx += 256) {
        int r = idx >> 7, c = idx & 127;
        xs[r * 132 + c] = x[((size_t)b * NN + nb + r) * DD + c];
    }
    __syncthreads();
    int o = tid & 127, rh = tid >> 7;   // rh in {0,1}: 16 n-rows each
    float acc[16];
#pragma unroll
    for (int j = 0; j < 16; ++j) acc[j] = 0.f;
    const float* Wc = W + (size_t)h * DD * DD + o;
    for (int i = 0; i < DD; i += 4) {
        float w0 = Wc[(i + 0) * DD];
        float w1 = Wc[(i + 1) * DD];
        float w2 = Wc[(i + 2) * DD];
        float w3 = Wc[(i + 3) * DD];
#pragma unroll
        for (int j = 0; j < 16; ++j) {
            float4 xq = *(const float4*)&xs[(rh * 16 + j) * 132 + i];
            acc[j] += xq.x * w0 + xq.y * w1 + xq.z * w2 + xq.w * w3;
        }
    }
    bf16x8 p0, p1;
#pragma unroll
    for (int j = 0; j < 8; ++j) { p0[j] = (short)f2bf(acc[j]); p1[j] = (short)f2bf(acc[8 + j]); }
    unsigned short* dst = hT + ((size_t)bh * DD + o) * NN + nb + rh * 16;
    *(bf16x8*)dst = p0;
    *(bf16x8*)(dst + 8) = p1;
}

// ---------------------------------------------------------------------------
// Kernel S: softmax stats per (b,n) row, all 4 heads. Branchless two-phase:
// M = lrelu(s + max_valid d) (exact: lrelu is monotone, softmax invariant to
// any stabilizer >= true max), then one exp-sum pass. Row cached in
// registers (8 m/thread); shuffle wave reductions, 3 barriers total.
// ---------------------------------------------------------------------------
__global__ __launch_bounds__(256) void k_stats(const int* __restrict__ adj,
                                               const float* __restrict__ s_in,
                                               const float* __restrict__ d_in_,
                                               float* __restrict__ M_out,
                                               float* __restrict__ Li_out) {
    __shared__ float part[4][4];    // [head][wave]
    int tid = threadIdx.x;
    int lane = tid & 63, w = tid >> 6;
    int b = blockIdx.x / NN, n = blockIdx.x % NN;
    const int* arow = adj + ((size_t)b * NN + n) * NN;
    int av[8];
#pragma unroll
    for (int k = 0; k < 8; ++k) av[k] = arow[tid + k * 256];
    float dv[8][4];
#pragma unroll
    for (int h = 0; h < 4; ++h) {
        const float* dp = d_in_ + (size_t)(b * HH + h) * NN;
#pragma unroll
        for (int k = 0; k < 8; ++k) dv[k][h] = dp[tid + k * 256];
    }
    float sv[4];
#pragma unroll
    for (int h = 0; h < 4; ++h) sv[h] = s_in[(b * HH + h) * NN + n];

    // phase 1: max of d over valid m (branchless select)
    float mx[4];
#pragma unroll
    for (int h = 0; h < 4; ++h) mx[h] = NEG_BIG;
#pragma unroll
    for (int k = 0; k < 8; ++k)
#pragma unroll
        for (int h = 0; h < 4; ++h)
            mx[h] = (av[k] != 0 && dv[k][h] > mx[h]) ? dv[k][h] : mx[h];
#pragma unroll
    for (int off = 32; off >= 1; off >>= 1)
#pragma unroll
        for (int h = 0; h < 4; ++h)
            mx[h] = fmaxf(mx[h], __shfl_xor(mx[h], off, 64));
    if (lane == 0)
#pragma unroll
        for (int h = 0; h < 4; ++h) part[h][w] = mx[h];
    __syncthreads();
    float M[4];
#pragma unroll
    for (int h = 0; h < 4; ++h) {
        float md = fmaxf(fmaxf(part[h][0], part[h][1]), fmaxf(part[h][2], part[h][3]));
        float t = sv[h] + md;
        M[h] = t > 0.f ? t : 0.2f * t;
    }
    __syncthreads();    // before reusing part[]

    // phase 2: exp-sum with known M
    float L[4] = {0.f, 0.f, 0.f, 0.f};
#pragma unroll
    for (int k = 0; k < 8; ++k)
#pragma unroll
        for (int h = 0; h < 4; ++h) {
            float t = sv[h] + dv[k][h];
            float v = t > 0.f ? t : 0.2f * t;
            float e = exp2f((v - M[h]) * LOG2E);
            L[h] += (av[k] != 0) ? e : 0.f;
        }
#pragma unroll
    for (int off = 32; off >= 1; off >>= 1)
#pragma unroll
        for (int h = 0; h < 4; ++h)
            L[h] += __shfl_xor(L[h], off, 64);
    if (lane == 0)
#pragma unroll
        for (int h = 0; h < 4; ++h) part[h][w] = L[h];
    __syncthreads();
    if (tid == 0) {
#pragma unroll
        for (int h = 0; h < 4; ++h) {
            float Lt = part[h][0] + part[h][1] + part[h][2] + part[h][3];
            M_out[(b * HH + h) * NN + n]  = M[h];
            Li_out[(b * HH + h) * NN + n] = Lt > 0.f ? 1.f / Lt : 0.f;
        }
    }
}

// ---------------------------------------------------------------------------
// Kernel 3 (MFMA): per (b,h,64-n-tile): C[64n][128o] = alpha @ h.
// LDS trimmed to 52 KB (d/s/M/Li read straight from L2). Plain
// __launch_bounds__(256): no VGPR cap gamble — if natural allocation is
// <=170 we get 3 blocks/CU anyway; if not, 2 blocks/CU without spills.
// WRITE_ALPHA=true additionally stores the fp32 normalized alpha tile to its
// final location (fuses away the old k_alpha pass: same exp, written once).
// ---------------------------------------------------------------------------
template <bool WRITE_ALPHA>
__global__ __launch_bounds__(256) void k_attn_mfma(const int* __restrict__ adj,
                                                   const float* __restrict__ s_in,
                                                   const float* __restrict__ d_in_,
                                                   const float* __restrict__ M_in,
                                                   const float* __restrict__ Li_in,
                                                   const unsigned short* __restrict__ hT,
                                                   float* __restrict__ out_scr,
                                                   float* __restrict__ alpha_out) {
    __shared__ unsigned short al_lds[64 * 136];    // alpha tile, +8 bf16 pad
    __shared__ unsigned short hT_lds[128 * 136];   // h chunk (o-major), +8 pad
    int tid = threadIdx.x;
    int bh = blockIdx.x >> 5;
    int nb = (blockIdx.x & 31) * 64;
    int b = bh >> 2;

    // phase-A mapping: thread -> (n row, 32-m segment)
    int an = tid >> 2, mseg = (tid & 3) * 32;
    float sn  = s_in[bh * NN + nb + an];
    float Mn  = M_in[bh * NN + nb + an];
    float Lin = Li_in[bh * NN + nb + an];
    const int* arow = adj + ((size_t)b * NN + nb + an) * NN;
    const float* dg = d_in_ + (size_t)bh * NN;                 // L2-hot 8 KB row
    float* alpha_row = alpha_out + ((size_t)bh * NN + nb + an) * NN;
    // phase-B mapping: thread -> (o row, 64-m half)
    int ho = tid >> 1, hhalf = (tid & 1) * 64;
    const unsigned short* hrow = hT + ((size_t)bh * DD + ho) * NN;
    // phase-C mapping: wave/lane
    int l = tid & 63, w = tid >> 6, col = l & 15, quad = l >> 4;

    f32x4 acc[8];
#pragma unroll
    for (int ot = 0; ot < 8; ++ot) acc[ot] = (f32x4){0.f, 0.f, 0.f, 0.f};

    for (int mb = 0; mb < NN; mb += 128) {
        __syncthreads();   // prev-stage MFMA reads complete before overwrite
        // --- phase A: alpha tile (bf16) into LDS A-layout (+ fp32 store) ---
        const int4* ap = (const int4*)(arow + mb + mseg);
#pragma unroll
        for (int g = 0; g < 4; ++g) {
            int4 a0 = ap[2 * g], a1 = ap[2 * g + 1];
            float4 d0 = *(const float4*)(dg + mb + mseg + g * 8);
            float4 d1 = *(const float4*)(dg + mb + mseg + g * 8 + 4);
            int   av[8] = {a0.x, a0.y, a0.z, a0.w, a1.x, a1.y, a1.z, a1.w};
            float dvv[8] = {d0.x, d0.y, d0.z, d0.w, d1.x, d1.y, d1.z, d1.w};
            bf16x8 pk;
            float ev[8];
#pragma unroll
            for (int j = 0; j < 8; ++j) {
                float t = sn + dvv[j];
                float v = t > 0.f ? t : 0.2f * t;
                float e = (av[j] != 0) ? exp2f((v - Mn) * LOG2E) * Lin : 0.f;
                ev[j] = e;
                pk[j] = (short)f2bf(e);
            }
            *(bf16x8*)&al_lds[an * 136 + mseg + g * 8] = pk;
            if (WRITE_ALPHA) {
                float4 e0; e0.x = ev[0]; e0.y = ev[1]; e0.z = ev[2]; e0.w = ev[3];
                float4 e1; e1.x = ev[4]; e1.y = ev[5]; e1.z = ev[6]; e1.w = ev[7];
                float4* aout = (float4*)(alpha_row + mb + mseg + g * 8);
                aout[0] = e0;
                aout[1] = e1;
            }
        }
        // --- phase B: stage hT chunk [128 o][128 m] ---
#pragma unroll
        for (int q = 0; q < 8; ++q) {
            bf16x8 hv = *(const bf16x8*)(hrow + mb + hhalf + q * 8);
            *(bf16x8*)&hT_lds[ho * 136 + hhalf + q * 8] = hv;
        }
        __syncthreads();
        // --- phase C: MFMA ---
#pragma unroll
        for (int k = 0; k < 4; ++k) {
            bf16x8 af = *(const bf16x8*)&al_lds[(w * 16 + col) * 136 + k * 32 + quad * 8];
#pragma unroll
            for (int ot = 0; ot < 8; ++ot) {
                bf16x8 bfv = *(const bf16x8*)&hT_lds[(ot * 16 + col) * 136 + k * 32 + quad * 8];
                acc[ot] = __builtin_amdgcn_mfma_f32_16x16x32_bf16(af, bfv, acc[ot], 0, 0, 0);
            }
        }
    }
    // epilogue: C/D layout col=lane&15, row=quad*4+reg
#pragma unroll
    for (int ot = 0; ot < 8; ++ot)
#pragma unroll
        for (int r = 0; r < 4; ++r)
            out_scr[((size_t)bh * NN + nb + w * 16 + quad * 4 + r) * DD + ot * 16 + col] =
                acc[ot][r];
}

// ---------------------------------------------------------------------------
// Kernel 4: output[b,n,o] = concat_h(out_scr) @ Wp + bias, fp32 store.
// 2 o-cols x 4 rows per thread; float4 LDS reads -> 1/4 the LDS issue.
// ---------------------------------------------------------------------------
__global__ __launch_bounds__(256) void k_proj(const float* __restrict__ out_scr,
                                              const float* __restrict__ Wp,
                                              const float* __restrict__ bias,
                                              float* __restrict__ out) {
    __shared__ float cs[16 * 512];
    int tid = threadIdx.x;
    int b  = blockIdx.x / (NN / 16);
    int nb = (blockIdx.x % (NN / 16)) * 16;
    for (int idx = tid; idx < 16 * 512; idx += 256) {
        int r = idx >> 9, c = idx & 511;
        int hh = c >> 7, oo = c & 127;
        cs[idx] = out_scr[((size_t)(b * HH + hh) * NN + nb + r) * DD + oo];
    }
    __syncthreads();
    int o = tid & 63, rg = tid >> 6;        // 4 row-groups x 4 rows
    float bv0 = bias[o], bv1 = bias[o + 64];
    float acc0[4], acc1[4];
#pragma unroll
    for (int j = 0; j < 4; ++j) { acc0[j] = bv0; acc1[j] = bv1; }
    for (int k = 0; k < 512; k += 4) {
        float w00 = Wp[(k + 0) * DD + o], w01 = Wp[(k + 0) * DD + o + 64];
        float w10 = Wp[(k + 1) * DD + o], w11 = Wp[(k + 1) * DD + o + 64];
        float w20 = Wp[(k + 2) * DD + o], w21 = Wp[(k + 2) * DD + o + 64];
        float w30 = Wp[(k + 3) * DD + o], w31 = Wp[(k + 3) * DD + o + 64];
#pragma unroll
        for (int j = 0; j < 4; ++j) {
            float4 cq = *(const float4*)&cs[(rg * 4 + j) * 512 + k];
            acc0[j] += cq.x * w00 + cq.y * w10 + cq.z * w20 + cq.w * w30;
            acc1[j] += cq.x * w01 + cq.y * w11 + cq.z * w21 + cq.w * w31;
        }
    }
#pragma unroll
    for (int j = 0; j < 4; ++j) {
        out[((size_t)b * NN + nb + rg * 4 + j) * DD + o]      = acc0[j];
        out[((size_t)b * NN + nb + rg * 4 + j) * DD + o + 64] = acc1[j];
    }
}

// ---------------------------------------------------------------------------
// Kernel 5 (fallback only): write final fp32 alpha over the (now-consumed)
// scratch. Used only when the workspace is too small to host hT/out_scr.
// ---------------------------------------------------------------------------
__global__ __launch_bounds__(256) void k_alpha(const int* __restrict__ adj,
                                               const float* __restrict__ s_in,
                                               const float* __restrict__ d_in_,
                                               const float* __restrict__ M_in,
                                               const float* __restrict__ Li_in,
                                               float* __restrict__ alpha_out) {
    int tid = threadIdx.x;
    int b = blockIdx.x / NN, n = blockIdx.x % NN;
    float sv[4], Mv[4], Lv[4];
#pragma unroll
    for (int h = 0; h < 4; ++h) {
        sv[h] = s_in[(b * HH + h) * NN + n];
        Mv[h] = M_in[(b * HH + h) * NN + n];
        Lv[h] = Li_in[(b * HH + h) * NN + n];
    }
    const int* arow = adj + ((size_t)b * NN + n) * NN;
    for (int m = tid; m < NN; m += 256) {
        int av = arow[m];
#pragma unroll
        for (int h = 0; h < 4; ++h) {
            float val = 0.f;
            if (av != 0) {
                float t = sv[h] + d_in_[(b * HH + h) * NN + m];
                float v = t > 0.f ? t : 0.2f * t;
                val = exp2f((v - Mv[h]) * LOG2E) * Lv[h];
            }
            alpha_out[((size_t)(b * HH + h) * NN + n) * NN + m] = val;
        }
    }
}

// ---------------------------------------------------------------------------
extern "C" void kernel_launch(void* const* d_in, const int* in_sizes, int n_in,
                              void* d_out, int out_size, void* d_ws, size_t ws_size,
                              hipStream_t stream) {
    const float* x    = (const float*)d_in[0];
    const int*   adj  = (const int*)d_in[1];
    const float* W    = (const float*)d_in[2];
    const float* a    = (const float*)d_in[3];
    const float* Wp   = (const float*)d_in[4];
    const float* bias = (const float*)d_in[5];

    float* out       = (float*)d_out;
    float* alpha_out = out + (size_t)BB * NN * DD;

    // Stats always live in the workspace head (528 KB).
    float* ws  = (float*)d_ws;
    float* wsv = ws;
    float* wdv = wsv + HH * DD;
    float* s_  = wdv + HH * DD;
    float* d_  = s_ + (size_t)BB * HH * NN;
    float* M_  = d_ + (size_t)BB * HH * NN;
    float* Li_ = M_ + (size_t)BB * HH * NN;

    const size_t stats_bytes = (2 * HH * DD + 4 * (size_t)BB * HH * NN) * sizeof(float);
    const size_t hT_bytes    = (size_t)BB * HH * NN * DD * sizeof(unsigned short);  // 8.39 MB
    const size_t scr_bytes   = (size_t)BB * HH * NN * DD * sizeof(float);           // 16.8 MB
    const bool fused = ws_size >= stats_bytes + hT_bytes + scr_bytes;

    unsigned short* hT;
    float* out_scr;
    if (fused) {
        // hT/out_scr in workspace -> alpha written in-place by k_attn_mfma.
        hT      = (unsigned short*)((char*)d_ws + stats_bytes);
        out_scr = (float*)((char*)hT + hT_bytes);
    } else {
        // Legacy layout: scratch inside the fp32 alpha region, k_alpha last.
        hT      = (unsigned short*)alpha_out;
        out_scr = alpha_out + (size_t)BB * HH * NN * DD;
    }

    k_wvec<<<HH, 128, 0, stream>>>(W, a, wsv, wdv);
    k_sd<<<BB * NN / 64, 256, 0, stream>>>(x, wsv, wdv, s_, d_);
    k_h<<<BB * HH * (NN / 32), 256, 0, stream>>>(x, W, hT);
    k_stats<<<BB * NN, 256, 0, stream>>>(adj, s_, d_, M_, Li_);
    if (fused) {
        k_attn_mfma<true><<<BB * HH * (NN / 64), 256, 0, stream>>>(adj, s_, d_, M_, Li_,
                                                                   hT, out_scr, alpha_out);
        k_proj<<<BB * (NN / 16), 256, 0, stream>>>(out_scr, Wp, bias, out);
    } else {
        k_attn_mfma<false><<<BB * HH * (NN / 64), 256, 0, stream>>>(adj, s_, d_, M_, Li_,
                                                                    hT, out_scr, alpha_out);
        k_proj<<<BB * (NN / 16), 256, 0, stream>>>(out_scr, Wp, bias, out);
        k_alpha<<<BB * NN, 256, 0, stream>>>(adj, s_, d_, M_, Li_, alpha_out);
    }
}

// Round 3
// 469.756 us; speedup vs baseline: 1.2807x; 1.2807x over previous
//
#include <hip/hip_runtime.h>
#include <hip/hip_bf16.h>

#define BB 4
#define NN 2048
#define DD 128
#define HH 4
#define LOG2E 1.4426950408889634f
#define NEG_BIG (-1e30f)

typedef __attribute__((ext_vector_type(8))) short bf16x8;   // 8 bf16 in 4 VGPRs
typedef __attribute__((ext_vector_type(4))) short bf16x4;   // 4 bf16 in 2 VGPRs
typedef __attribute__((ext_vector_type(4))) float f32x4;    // MFMA accumulator

__device__ __forceinline__ unsigned short f2bf(float f) {
    union { float f; unsigned int u; } v; v.f = f;
    unsigned int r = v.u + 0x7FFF + ((v.u >> 16) & 1);      // round-nearest-even
    return (unsigned short)(r >> 16);
}

// ---------------------------------------------------------------------------
// Kernel A: wsv[h][i] = sum_o W[h,i,o]*a[h,o]; wdv likewise with a[h,D+o].
// ---------------------------------------------------------------------------
__global__ __launch_bounds__(128) void k_wvec(const float* __restrict__ W,
                                              const float* __restrict__ a,
                                              float* __restrict__ wsv,
                                              float* __restrict__ wdv) {
    int h = blockIdx.x;
    int i = threadIdx.x;
    const float* Wr  = W + (h * DD + i) * DD;
    const float* as_ = a + h * 2 * DD;
    const float* ad_ = as_ + DD;
    float s = 0.f, d = 0.f;
    for (int o = 0; o < DD; ++o) {
        float w = Wr[o];
        s += w * as_[o];
        d += w * ad_[o];
    }
    wsv[h * DD + i] = s;
    wdv[h * DD + i] = d;
}

// ---------------------------------------------------------------------------
// Kernel B: s[b,h,n] = x[b,n,:] . wsv[h]; d likewise. 64 rows/block.
// ---------------------------------------------------------------------------
__global__ __launch_bounds__(256) void k_sd(const float* __restrict__ x,
                                            const float* __restrict__ wsv,
                                            const float* __restrict__ wdv,
                                            float* __restrict__ s_out,
                                            float* __restrict__ d_out_) {
    __shared__ float xs[64 * 129];
    __shared__ float ws[4 * 129], wd[4 * 129];
    int tid = threadIdx.x;
    int b  = blockIdx.x / (NN / 64);
    int nb = (blockIdx.x % (NN / 64)) * 64;
    for (int idx = tid; idx < HH * DD; idx += 256) {
        ws[(idx >> 7) * 129 + (idx & 127)] = wsv[idx];
        wd[(idx >> 7) * 129 + (idx & 127)] = wdv[idx];
    }
    for (int idx = tid; idx < 64 * 128; idx += 256) {
        int r = idx >> 7, c = idx & 127;
        xs[r * 129 + c] = x[((size_t)b * NN + nb + r) * DD + c];
    }
    __syncthreads();
    int h = tid & 3, r = tid >> 2;
    float sv = 0.f, dv = 0.f;
#pragma unroll 8
    for (int i = 0; i < DD; ++i) {
        float xv = xs[r * 129 + i];
        sv += xv * ws[h * 129 + i];
        dv += xv * wd[h * 129 + i];
    }
    int n = nb + r;
    s_out[(b * HH + h) * NN + n] = sv;
    d_out_[(b * HH + h) * NN + n] = dv;
}

// ---------------------------------------------------------------------------
// Kernel H: h[b,h,n,o] = sum_i x[b,n,i]*W[h,i,o]; stored TRANSPOSED as bf16:
// hT[bh][o][n] (n contiguous) — the MFMA B-operand layout for k_attn_mfma.
// ---------------------------------------------------------------------------
__global__ __launch_bounds__(256) void k_h(const float* __restrict__ x,
                                           const float* __restrict__ W,
                                           unsigned short* __restrict__ hT) {
    __shared__ float xs[32 * 132];
    int tid = threadIdx.x;
    int bh = blockIdx.x / (NN / 32);
    int nb = (blockIdx.x % (NN / 32)) * 32;
    int b = bh >> 2, h = bh & 3;
    for (int idx = tid; idx < 32 * 128; idx += 256) {
        int r = idx >> 7, c = idx & 127;
        xs[r * 132 + c] = x[((size_t)b * NN + nb + r) * DD + c];
    }
    __syncthreads();
    int o = tid & 127, rh = tid >> 7;   // rh in {0,1}: 16 n-rows each
    float acc[16];
#pragma unroll
    for (int j = 0; j < 16; ++j) acc[j] = 0.f;
    const float* Wc = W + (size_t)h * DD * DD + o;
    for (int i = 0; i < DD; i += 4) {
        float w0 = Wc[(i + 0) * DD];
        float w1 = Wc[(i + 1) * DD];
        float w2 = Wc[(i + 2) * DD];
        float w3 = Wc[(i + 3) * DD];
#pragma unroll
        for (int j = 0; j < 16; ++j) {
            float4 xq = *(const float4*)&xs[(rh * 16 + j) * 132 + i];
            acc[j] += xq.x * w0 + xq.y * w1 + xq.z * w2 + xq.w * w3;
        }
    }
    bf16x8 p0, p1;
#pragma unroll
    for (int j = 0; j < 8; ++j) { p0[j] = (short)f2bf(acc[j]); p1[j] = (short)f2bf(acc[8 + j]); }
    unsigned short* dst = hT + ((size_t)bh * DD + o) * NN + nb + rh * 16;
    *(bf16x8*)dst = p0;
    *(bf16x8*)(dst + 8) = p1;
}

// ---------------------------------------------------------------------------
// Kernel S: softmax stats per (b,n) row, all 4 heads. Branchless two-phase.
// ---------------------------------------------------------------------------
__global__ __launch_bounds__(256) void k_stats(const int* __restrict__ adj,
                                               const float* __restrict__ s_in,
                                               const float* __restrict__ d_in_,
                                               float* __restrict__ M_out,
                                               float* __restrict__ Li_out) {
    __shared__ float part[4][4];    // [head][wave]
    int tid = threadIdx.x;
    int lane = tid & 63, w = tid >> 6;
    int b = blockIdx.x / NN, n = blockIdx.x % NN;
    const int* arow = adj + ((size_t)b * NN + n) * NN;
    int av[8];
#pragma unroll
    for (int k = 0; k < 8; ++k) av[k] = arow[tid + k * 256];
    float dv[8][4];
#pragma unroll
    for (int h = 0; h < 4; ++h) {
        const float* dp = d_in_ + (size_t)(b * HH + h) * NN;
#pragma unroll
        for (int k = 0; k < 8; ++k) dv[k][h] = dp[tid + k * 256];
    }
    float sv[4];
#pragma unroll
    for (int h = 0; h < 4; ++h) sv[h] = s_in[(b * HH + h) * NN + n];

    float mx[4];
#pragma unroll
    for (int h = 0; h < 4; ++h) mx[h] = NEG_BIG;
#pragma unroll
    for (int k = 0; k < 8; ++k)
#pragma unroll
        for (int h = 0; h < 4; ++h)
            mx[h] = (av[k] != 0 && dv[k][h] > mx[h]) ? dv[k][h] : mx[h];
#pragma unroll
    for (int off = 32; off >= 1; off >>= 1)
#pragma unroll
        for (int h = 0; h < 4; ++h)
            mx[h] = fmaxf(mx[h], __shfl_xor(mx[h], off, 64));
    if (lane == 0)
#pragma unroll
        for (int h = 0; h < 4; ++h) part[h][w] = mx[h];
    __syncthreads();
    float M[4];
#pragma unroll
    for (int h = 0; h < 4; ++h) {
        float md = fmaxf(fmaxf(part[h][0], part[h][1]), fmaxf(part[h][2], part[h][3]));
        float t = sv[h] + md;
        M[h] = t > 0.f ? t : 0.2f * t;
    }
    __syncthreads();

    float L[4] = {0.f, 0.f, 0.f, 0.f};
#pragma unroll
    for (int k = 0; k < 8; ++k)
#pragma unroll
        for (int h = 0; h < 4; ++h) {
            float t = sv[h] + dv[k][h];
            float v = t > 0.f ? t : 0.2f * t;
            float e = exp2f((v - M[h]) * LOG2E);
            L[h] += (av[k] != 0) ? e : 0.f;
        }
#pragma unroll
    for (int off = 32; off >= 1; off >>= 1)
#pragma unroll
        for (int h = 0; h < 4; ++h)
            L[h] += __shfl_xor(L[h], off, 64);
    if (lane == 0)
#pragma unroll
        for (int h = 0; h < 4; ++h) part[h][w] = L[h];
    __syncthreads();
    if (tid == 0) {
#pragma unroll
        for (int h = 0; h < 4; ++h) {
            float Lt = part[h][0] + part[h][1] + part[h][2] + part[h][3];
            M_out[(b * HH + h) * NN + n]  = M[h];
            Li_out[(b * HH + h) * NN + n] = Lt > 0.f ? 1.f / Lt : 0.f;
        }
    }
}

// ---------------------------------------------------------------------------
// Kernel 3 (MFMA): per (b,h,64-n-tile): C[64n][128o] = alpha @ h.
// Round-2 rework from counters (WRITE 508MB vs 285 logical, 7.9M bank-conf):
//  * phase A remapped to wave-coalesced rows: pass p -> row = p*8 + (tid>>5),
//    cols (tid&31)*4. Alpha float4 stores are 1KB contiguous per wave ->
//    full-line write streams (no 16B scatter -> no partial-burst blowup).
//  * adj int4 loads likewise 1KB contiguous; d loaded ONCE per m-tile.
//  * LDS pads removed; XOR swizzle byte ^= ((row&15)<<4) on both tiles ->
//    conflict-free ds_read_b128 in phase C (each 8-lane group hits all 32
//    banks once). LDS 49KB -> still 3 blocks/CU.
//  * all global loads of the m-tile issued up-front (latency overlap).
// ---------------------------------------------------------------------------
template <bool WRITE_ALPHA>
__global__ __launch_bounds__(256) void k_attn_mfma(const int* __restrict__ adj,
                                                   const float* __restrict__ s_in,
                                                   const float* __restrict__ d_in_,
                                                   const float* __restrict__ M_in,
                                                   const float* __restrict__ Li_in,
                                                   const unsigned short* __restrict__ hT,
                                                   float* __restrict__ out_scr,
                                                   float* __restrict__ alpha_out) {
    __shared__ unsigned short al_lds[64 * 128];    // XOR-swizzled, no pad
    __shared__ unsigned short hT_lds[128 * 128];   // XOR-swizzled, no pad
    __shared__ float srow[64], Mrow[64], Lirow[64];
    int tid = threadIdx.x;
    int bh = blockIdx.x >> 5;
    int nb = (blockIdx.x & 31) * 64;
    int b = bh >> 2;

    if (tid < 64) {
        srow[tid]  = s_in[bh * NN + nb + tid];
        Mrow[tid]  = M_in[bh * NN + nb + tid];
        Lirow[tid] = Li_in[bh * NN + nb + tid];
    }

    // phase-A mapping: 8 passes; pass p: row = p*8 + ar0, float-col = ac4..ac4+3
    int ar0 = tid >> 5;                 // 0..7
    int ac4 = (tid & 31) * 4;           // 0..124
    const int* adj_base = adj + ((size_t)b * NN + nb + ar0) * NN + ac4;
    float* alpha_base = WRITE_ALPHA
        ? alpha_out + ((size_t)bh * NN + nb + ar0) * NN + ac4 : nullptr;
    const float* dg = d_in_ + (size_t)bh * NN;     // L2-hot 8 KB row
    // phase-B mapping: thread -> (o row, 64-m half)
    int ho = tid >> 1, hhalf = (tid & 1) * 64;
    const unsigned short* hrow = hT + ((size_t)bh * DD + ho) * NN;
    // phase-C mapping: wave/lane
    int l = tid & 63, w = tid >> 6, col = l & 15, quad = l >> 4;

    f32x4 acc[8];
#pragma unroll
    for (int ot = 0; ot < 8; ++ot) acc[ot] = (f32x4){0.f, 0.f, 0.f, 0.f};

    for (int mb = 0; mb < NN; mb += 128) {
        __syncthreads();   // prev-stage MFMA reads complete; srow ready (iter 0)

        // ---- issue ALL global loads for this m-tile up front ----
        int4 a4[8];
#pragma unroll
        for (int p = 0; p < 8; ++p)
            a4[p] = *(const int4*)(adj_base + (size_t)(p * 8) * NN + mb);
        float4 d4 = *(const float4*)(dg + mb + ac4);
        bf16x8 hv[8];
#pragma unroll
        for (int q = 0; q < 8; ++q)
            hv[q] = *(const bf16x8*)(hrow + mb + hhalf + q * 8);

        // ---- phase A: alpha (bf16 -> LDS swizzled; fp32 -> coalesced store)
#pragma unroll
        for (int p = 0; p < 8; ++p) {
            int row = p * 8 + ar0;
            float sn = srow[row], Mn = Mrow[row], Lin = Lirow[row];
            float t0 = sn + d4.x, t1 = sn + d4.y, t2 = sn + d4.z, t3 = sn + d4.w;
            float v0 = t0 > 0.f ? t0 : 0.2f * t0;
            float v1 = t1 > 0.f ? t1 : 0.2f * t1;
            float v2 = t2 > 0.f ? t2 : 0.2f * t2;
            float v3 = t3 > 0.f ? t3 : 0.2f * t3;
            float e0 = (a4[p].x != 0) ? exp2f((v0 - Mn) * LOG2E) * Lin : 0.f;
            float e1 = (a4[p].y != 0) ? exp2f((v1 - Mn) * LOG2E) * Lin : 0.f;
            float e2 = (a4[p].z != 0) ? exp2f((v2 - Mn) * LOG2E) * Lin : 0.f;
            float e3 = (a4[p].w != 0) ? exp2f((v3 - Mn) * LOG2E) * Lin : 0.f;
            bf16x4 pk;
            pk[0] = (short)f2bf(e0); pk[1] = (short)f2bf(e1);
            pk[2] = (short)f2bf(e2); pk[3] = (short)f2bf(e3);
            int abyte = (ac4 * 2) ^ ((row & 15) << 4);      // swizzled byte-in-row
            *(bf16x4*)&al_lds[row * 128 + (abyte >> 1)] = pk;
            if (WRITE_ALPHA) {
                float4 ev; ev.x = e0; ev.y = e1; ev.z = e2; ev.w = e3;
                *(float4*)(alpha_base + (size_t)(p * 8) * NN + mb) = ev;
            }
        }
        // ---- phase B: stage hT chunk [128 o][128 m], swizzled ----
#pragma unroll
        for (int q = 0; q < 8; ++q) {
            int hbyte = (hhalf * 2 + q * 16) ^ ((ho & 15) << 4);
            *(bf16x8*)&hT_lds[ho * 128 + (hbyte >> 1)] = hv[q];
        }
        __syncthreads();
        // ---- phase C: MFMA (swizzled reads; row&15 == col for both tiles) --
#pragma unroll
        for (int k = 0; k < 4; ++k) {
            int cbyte = (k * 64 + quad * 16) ^ (col << 4);
            bf16x8 af = *(const bf16x8*)&al_lds[(w * 16 + col) * 128 + (cbyte >> 1)];
#pragma unroll
            for (int ot = 0; ot < 8; ++ot) {
                bf16x8 bfv = *(const bf16x8*)&hT_lds[(ot * 16 + col) * 128 + (cbyte >> 1)];
                acc[ot] = __builtin_amdgcn_mfma_f32_16x16x32_bf16(af, bfv, acc[ot], 0, 0, 0);
            }
        }
    }
    // epilogue: C/D layout col=lane&15, row=quad*4+reg
#pragma unroll
    for (int ot = 0; ot < 8; ++ot)
#pragma unroll
        for (int r = 0; r < 4; ++r)
            out_scr[((size_t)bh * NN + nb + w * 16 + quad * 4 + r) * DD + ot * 16 + col] =
                acc[ot][r];
}

// ---------------------------------------------------------------------------
// Kernel 4: output[b,n,o] = concat_h(out_scr) @ Wp + bias, fp32 store.
// ---------------------------------------------------------------------------
__global__ __launch_bounds__(256) void k_proj(const float* __restrict__ out_scr,
                                              const float* __restrict__ Wp,
                                              const float* __restrict__ bias,
                                              float* __restrict__ out) {
    __shared__ float cs[16 * 512];
    int tid = threadIdx.x;
    int b  = blockIdx.x / (NN / 16);
    int nb = (blockIdx.x % (NN / 16)) * 16;
    for (int idx = tid; idx < 16 * 512; idx += 256) {
        int r = idx >> 9, c = idx & 511;
        int hh = c >> 7, oo = c & 127;
        cs[idx] = out_scr[((size_t)(b * HH + hh) * NN + nb + r) * DD + oo];
    }
    __syncthreads();
    int o = tid & 63, rg = tid >> 6;        // 4 row-groups x 4 rows
    float bv0 = bias[o], bv1 = bias[o + 64];
    float acc0[4], acc1[4];
#pragma unroll
    for (int j = 0; j < 4; ++j) { acc0[j] = bv0; acc1[j] = bv1; }
    for (int k = 0; k < 512; k += 4) {
        float w00 = Wp[(k + 0) * DD + o], w01 = Wp[(k + 0) * DD + o + 64];
        float w10 = Wp[(k + 1) * DD + o], w11 = Wp[(k + 1) * DD + o + 64];
        float w20 = Wp[(k + 2) * DD + o], w21 = Wp[(k + 2) * DD + o + 64];
        float w30 = Wp[(k + 3) * DD + o], w31 = Wp[(k + 3) * DD + o + 64];
#pragma unroll
        for (int j = 0; j < 4; ++j) {
            float4 cq = *(const float4*)&cs[(rg * 4 + j) * 512 + k];
            acc0[j] += cq.x * w00 + cq.y * w10 + cq.z * w20 + cq.w * w30;
            acc1[j] += cq.x * w01 + cq.y * w11 + cq.z * w21 + cq.w * w31;
        }
    }
#pragma unroll
    for (int j = 0; j < 4; ++j) {
        out[((size_t)b * NN + nb + rg * 4 + j) * DD + o]      = acc0[j];
        out[((size_t)b * NN + nb + rg * 4 + j) * DD + o + 64] = acc1[j];
    }
}

// ---------------------------------------------------------------------------
// Kernel 5 (fallback only): write final fp32 alpha over the (now-consumed)
// scratch. Used only when the workspace is too small to host hT/out_scr.
// ---------------------------------------------------------------------------
__global__ __launch_bounds__(256) void k_alpha(const int* __restrict__ adj,
                                               const float* __restrict__ s_in,
                                               const float* __restrict__ d_in_,
                                               const float* __restrict__ M_in,
                                               const float* __restrict__ Li_in,
                                               float* __restrict__ alpha_out) {
    int tid = threadIdx.x;
    int b = blockIdx.x / NN, n = blockIdx.x % NN;
    float sv[4], Mv[4], Lv[4];
#pragma unroll
    for (int h = 0; h < 4; ++h) {
        sv[h] = s_in[(b * HH + h) * NN + n];
        Mv[h] = M_in[(b * HH + h) * NN + n];
        Lv[h] = Li_in[(b * HH + h) * NN + n];
    }
    const int* arow = adj + ((size_t)b * NN + n) * NN;
    for (int m = tid; m < NN; m += 256) {
        int av = arow[m];
#pragma unroll
        for (int h = 0; h < 4; ++h) {
            float val = 0.f;
            if (av != 0) {
                float t = sv[h] + d_in_[(b * HH + h) * NN + m];
                float v = t > 0.f ? t : 0.2f * t;
                val = exp2f((v - Mv[h]) * LOG2E) * Lv[h];
            }
            alpha_out[((size_t)(b * HH + h) * NN + n) * NN + m] = val;
        }
    }
}

// ---------------------------------------------------------------------------
extern "C" void kernel_launch(void* const* d_in, const int* in_sizes, int n_in,
                              void* d_out, int out_size, void* d_ws, size_t ws_size,
                              hipStream_t stream) {
    const float* x    = (const float*)d_in[0];
    const int*   adj  = (const int*)d_in[1];
    const float* W    = (const float*)d_in[2];
    const float* a    = (const float*)d_in[3];
    const float* Wp   = (const float*)d_in[4];
    const float* bias = (const float*)d_in[5];

    float* out       = (float*)d_out;
    float* alpha_out = out + (size_t)BB * NN * DD;

    // Stats always live in the workspace head (528 KB).
    float* ws  = (float*)d_ws;
    float* wsv = ws;
    float* wdv = wsv + HH * DD;
    float* s_  = wdv + HH * DD;
    float* d_  = s_ + (size_t)BB * HH * NN;
    float* M_  = d_ + (size_t)BB * HH * NN;
    float* Li_ = M_ + (size_t)BB * HH * NN;

    const size_t stats_bytes = (2 * HH * DD + 4 * (size_t)BB * HH * NN) * sizeof(float);
    const size_t hT_bytes    = (size_t)BB * HH * NN * DD * sizeof(unsigned short);  // 8.39 MB
    const size_t scr_bytes   = (size_t)BB * HH * NN * DD * sizeof(float);           // 16.8 MB
    const bool fused = ws_size >= stats_bytes + hT_bytes + scr_bytes;

    unsigned short* hT;
    float* out_scr;
    if (fused) {
        hT      = (unsigned short*)((char*)d_ws + stats_bytes);
        out_scr = (float*)((char*)hT + hT_bytes);
    } else {
        hT      = (unsigned short*)alpha_out;
        out_scr = alpha_out + (size_t)BB * HH * NN * DD;
    }

    k_wvec<<<HH, 128, 0, stream>>>(W, a, wsv, wdv);
    k_sd<<<BB * NN / 64, 256, 0, stream>>>(x, wsv, wdv, s_, d_);
    k_h<<<BB * HH * (NN / 32), 256, 0, stream>>>(x, W, hT);
    k_stats<<<BB * NN, 256, 0, stream>>>(adj, s_, d_, M_, Li_);
    if (fused) {
        k_attn_mfma<true><<<BB * HH * (NN / 64), 256, 0, stream>>>(adj, s_, d_, M_, Li_,
                                                                   hT, out_scr, alpha_out);
        k_proj<<<BB * (NN / 16), 256, 0, stream>>>(out_scr, Wp, bias, out);
    } else {
        k_attn_mfma<false><<<BB * HH * (NN / 64), 256, 0, stream>>>(adj, s_, d_, M_, Li_,
                                                                    hT, out_scr, alpha_out);
        k_proj<<<BB * (NN / 16), 256, 0, stream>>>(out_scr, Wp, bias, out);
        k_alpha<<<BB * NN, 256, 0, stream>>>(adj, s_, d_, M_, Li_, alpha_out);
    }
}

// Round 4
// 454.937 us; speedup vs baseline: 1.3224x; 1.0326x over previous
//
#include <hip/hip_runtime.h>
#include <hip/hip_bf16.h>

#define BB 4
#define NN 2048
#define DD 128
#define HH 4
#define LOG2E 1.4426950408889634f
#define NEG_BIG (-1e30f)

typedef __attribute__((ext_vector_type(8))) short bf16x8;   // 8 bf16 in 4 VGPRs
typedef __attribute__((ext_vector_type(4))) short bf16x4;   // 4 bf16 in 2 VGPRs
typedef __attribute__((ext_vector_type(4))) float f32x4;    // MFMA accumulator

__device__ __forceinline__ unsigned short f2bf(float f) {
    union { float f; unsigned int u; } v; v.f = f;
    unsigned int r = v.u + 0x7FFF + ((v.u >> 16) & 1);      // round-nearest-even
    return (unsigned short)(r >> 16);
}

// ---------------------------------------------------------------------------
// Kernel A: wsv[h][i] = sum_o W[h,i,o]*a[h,o]; wdv likewise with a[h,D+o].
// ---------------------------------------------------------------------------
__global__ __launch_bounds__(128) void k_wvec(const float* __restrict__ W,
                                              const float* __restrict__ a,
                                              float* __restrict__ wsv,
                                              float* __restrict__ wdv) {
    int h = blockIdx.x;
    int i = threadIdx.x;
    const float* Wr  = W + (h * DD + i) * DD;
    const float* as_ = a + h * 2 * DD;
    const float* ad_ = as_ + DD;
    float s = 0.f, d = 0.f;
    for (int o = 0; o < DD; ++o) {
        float w = Wr[o];
        s += w * as_[o];
        d += w * ad_[o];
    }
    wsv[h * DD + i] = s;
    wdv[h * DD + i] = d;
}

// ---------------------------------------------------------------------------
// Kernel H (now also fuses old k_sd): h[b,h,n,o] = sum_i x[b,n,i]*W[h,i,o],
// stored TRANSPOSED bf16 hT[bh][o][n]; plus s,d row dots (x staged anyway).
// ---------------------------------------------------------------------------
__global__ __launch_bounds__(256) void k_h(const float* __restrict__ x,
                                           const float* __restrict__ W,
                                           const float* __restrict__ wsv,
                                           const float* __restrict__ wdv,
                                           unsigned short* __restrict__ hT,
                                           float* __restrict__ s_out,
                                           float* __restrict__ d_out_) {
    __shared__ float xs[32 * 132];
    int tid = threadIdx.x;
    int bh = blockIdx.x / (NN / 32);
    int nb = (blockIdx.x % (NN / 32)) * 32;
    int b = bh >> 2, h = bh & 3;
    for (int idx = tid; idx < 32 * 128; idx += 256) {
        int r = idx >> 7, c = idx & 127;
        xs[r * 132 + c] = x[((size_t)b * NN + nb + r) * DD + c];
    }
    __syncthreads();
    int o = tid & 127, rh = tid >> 7;   // rh in {0,1}: 16 n-rows each
    float acc[16];
#pragma unroll
    for (int j = 0; j < 16; ++j) acc[j] = 0.f;
    const float* Wc = W + (size_t)h * DD * DD + o;
    for (int i = 0; i < DD; i += 4) {
        float w0 = Wc[(i + 0) * DD];
        float w1 = Wc[(i + 1) * DD];
        float w2 = Wc[(i + 2) * DD];
        float w3 = Wc[(i + 3) * DD];
#pragma unroll
        for (int j = 0; j < 16; ++j) {
            float4 xq = *(const float4*)&xs[(rh * 16 + j) * 132 + i];
            acc[j] += xq.x * w0 + xq.y * w1 + xq.z * w2 + xq.w * w3;
        }
    }
    bf16x8 p0, p1;
#pragma unroll
    for (int j = 0; j < 8; ++j) { p0[j] = (short)f2bf(acc[j]); p1[j] = (short)f2bf(acc[8 + j]); }
    unsigned short* dst = hT + ((size_t)bh * DD + o) * NN + nb + rh * 16;
    *(bf16x8*)dst = p0;
    *(bf16x8*)(dst + 8) = p1;

    // --- fused k_sd: s,d for these 32 rows (8 threads/row, 16-elem segments)
    {
        int r = tid >> 3, seg = (tid & 7) * 16;
        const float* wsp = wsv + h * DD + seg;
        const float* wdp = wdv + h * DD + seg;
        float sv = 0.f, dv = 0.f;
#pragma unroll
        for (int j = 0; j < 16; j += 4) {
            float4 xq = *(const float4*)&xs[r * 132 + seg + j];
            float4 wq = *(const float4*)(wsp + j);
            float4 vq = *(const float4*)(wdp + j);
            sv += xq.x * wq.x + xq.y * wq.y + xq.z * wq.z + xq.w * wq.w;
            dv += xq.x * vq.x + xq.y * vq.y + xq.z * vq.z + xq.w * vq.w;
        }
#pragma unroll
        for (int off = 1; off < 8; off <<= 1) {
            sv += __shfl_xor(sv, off, 64);
            dv += __shfl_xor(dv, off, 64);
        }
        if ((tid & 7) == 0) {
            s_out[(b * HH + h) * NN + nb + r]  = sv;
            d_out_[(b * HH + h) * NN + nb + r] = dv;
        }
    }
}

// ---------------------------------------------------------------------------
// Kernel S: softmax stats per (b,n) row, all 4 heads. Branchless two-phase.
// ---------------------------------------------------------------------------
__global__ __launch_bounds__(256) void k_stats(const int* __restrict__ adj,
                                               const float* __restrict__ s_in,
                                               const float* __restrict__ d_in_,
                                               float* __restrict__ M_out,
                                               float* __restrict__ Li_out) {
    __shared__ float part[4][4];    // [head][wave]
    int tid = threadIdx.x;
    int lane = tid & 63, w = tid >> 6;
    int b = blockIdx.x / NN, n = blockIdx.x % NN;
    const int* arow = adj + ((size_t)b * NN + n) * NN;
    int av[8];
#pragma unroll
    for (int k = 0; k < 8; ++k) av[k] = arow[tid + k * 256];
    float dv[8][4];
#pragma unroll
    for (int h = 0; h < 4; ++h) {
        const float* dp = d_in_ + (size_t)(b * HH + h) * NN;
#pragma unroll
        for (int k = 0; k < 8; ++k) dv[k][h] = dp[tid + k * 256];
    }
    float sv[4];
#pragma unroll
    for (int h = 0; h < 4; ++h) sv[h] = s_in[(b * HH + h) * NN + n];

    float mx[4];
#pragma unroll
    for (int h = 0; h < 4; ++h) mx[h] = NEG_BIG;
#pragma unroll
    for (int k = 0; k < 8; ++k)
#pragma unroll
        for (int h = 0; h < 4; ++h)
            mx[h] = (av[k] != 0 && dv[k][h] > mx[h]) ? dv[k][h] : mx[h];
#pragma unroll
    for (int off = 32; off >= 1; off >>= 1)
#pragma unroll
        for (int h = 0; h < 4; ++h)
            mx[h] = fmaxf(mx[h], __shfl_xor(mx[h], off, 64));
    if (lane == 0)
#pragma unroll
        for (int h = 0; h < 4; ++h) part[h][w] = mx[h];
    __syncthreads();
    float M[4];
#pragma unroll
    for (int h = 0; h < 4; ++h) {
        float md = fmaxf(fmaxf(part[h][0], part[h][1]), fmaxf(part[h][2], part[h][3]));
        float t = sv[h] + md;
        M[h] = t > 0.f ? t : 0.2f * t;
    }
    __syncthreads();

    float L[4] = {0.f, 0.f, 0.f, 0.f};
#pragma unroll
    for (int k = 0; k < 8; ++k)
#pragma unroll
        for (int h = 0; h < 4; ++h) {
            float t = sv[h] + dv[k][h];
            float v = t > 0.f ? t : 0.2f * t;
            float e = exp2f((v - M[h]) * LOG2E);
            L[h] += (av[k] != 0) ? e : 0.f;
        }
#pragma unroll
    for (int off = 32; off >= 1; off >>= 1)
#pragma unroll
        for (int h = 0; h < 4; ++h)
            L[h] += __shfl_xor(L[h], off, 64);
    if (lane == 0)
#pragma unroll
        for (int h = 0; h < 4; ++h) part[h][w] = L[h];
    __syncthreads();
    if (tid == 0) {
#pragma unroll
        for (int h = 0; h < 4; ++h) {
            float Lt = part[h][0] + part[h][1] + part[h][2] + part[h][3];
            M_out[(b * HH + h) * NN + n]  = M[h];
            Li_out[(b * HH + h) * NN + n] = Lt > 0.f ? 1.f / Lt : 0.f;
        }
    }
}

// ---------------------------------------------------------------------------
// Kernel 3 (MFMA): per (b,h,64-n-tile): C[64n][128o] = alpha @ h.
// Round-3 pipeline: register double-buffer (TileRegs R0/R1); loads for tile
// t+1 issue BEFORE the MFMA barrier of tile t (latency hides under MFMA —
// grid is 2 blocks/CU so TLP alone can't). Phase-B loads re-mapped to 16
// lanes x 16B = 256B/row contiguous. XCD-swizzled blockIdx: each XCD owns
// 2 bh values -> hT/adj L2-resident.
// ---------------------------------------------------------------------------
struct TileRegs {
    int4   a4[8];
    float4 d4;
    bf16x8 hv[8];
};

__device__ __forceinline__ void attn_load_tile(int mb, const int* adj_base,
                                               const float* dg, int ac4,
                                               const unsigned short* hbase,
                                               TileRegs& R) {
#pragma unroll
    for (int p = 0; p < 8; ++p)
        R.a4[p] = *(const int4*)(adj_base + (size_t)(p * 8) * NN + mb);
    R.d4 = *(const float4*)(dg + mb + ac4);
#pragma unroll
    for (int q = 0; q < 8; ++q)
        R.hv[q] = *(const bf16x8*)(hbase + (size_t)(q * 16) * NN + mb);
}

template <bool WRITE_ALPHA>
__device__ __forceinline__ void attn_tile_body(
    int mb, TileRegs& cur, TileRegs& nxt,
    const int* adj_base, const float* dg, int ac4,
    const unsigned short* hbase,
    unsigned short* al_lds, unsigned short* hT_lds,
    const float* srow, const float* Mrow, const float* Lirow,
    float* alpha_base, int ar0, int hrow0, int hbyte,
    int w, int col, int quad, f32x4 (&acc)[8])
{
    // ---- phase A: alpha (bf16 -> LDS swizzled; fp32 -> coalesced store) ----
#pragma unroll
    for (int p = 0; p < 8; ++p) {
        int row = p * 8 + ar0;
        float sn = srow[row], Mn = Mrow[row], Lin = Lirow[row];
        float t0 = sn + cur.d4.x, t1 = sn + cur.d4.y;
        float t2 = sn + cur.d4.z, t3 = sn + cur.d4.w;
        float v0 = t0 > 0.f ? t0 : 0.2f * t0;
        float v1 = t1 > 0.f ? t1 : 0.2f * t1;
        float v2 = t2 > 0.f ? t2 : 0.2f * t2;
        float v3 = t3 > 0.f ? t3 : 0.2f * t3;
        float e0 = (cur.a4[p].x != 0) ? exp2f((v0 - Mn) * LOG2E) * Lin : 0.f;
        float e1 = (cur.a4[p].y != 0) ? exp2f((v1 - Mn) * LOG2E) * Lin : 0.f;
        float e2 = (cur.a4[p].z != 0) ? exp2f((v2 - Mn) * LOG2E) * Lin : 0.f;
        float e3 = (cur.a4[p].w != 0) ? exp2f((v3 - Mn) * LOG2E) * Lin : 0.f;
        bf16x4 pk;
        pk[0] = (short)f2bf(e0); pk[1] = (short)f2bf(e1);
        pk[2] = (short)f2bf(e2); pk[3] = (short)f2bf(e3);
        int abyte = (ac4 * 2) ^ ((row & 15) << 4);      // swizzled byte-in-row
        *(bf16x4*)&al_lds[row * 128 + (abyte >> 1)] = pk;
        if (WRITE_ALPHA) {
            float4 ev; ev.x = e0; ev.y = e1; ev.z = e2; ev.w = e3;
            *(float4*)(alpha_base + (size_t)(p * 8) * NN + mb) = ev;
        }
    }
    // ---- phase B: stage hT chunk [128 o][128 m], swizzled ----
#pragma unroll
    for (int q = 0; q < 8; ++q)
        *(bf16x8*)&hT_lds[(q * 16 + hrow0) * 128 + (hbyte >> 1)] = cur.hv[q];

    // ---- prefetch next tile into nxt (in flight across barrier + MFMA) ----
    attn_load_tile((mb + 128) & (NN - 1), adj_base, dg, ac4, hbase, nxt);

    __syncthreads();
    // ---- phase C: MFMA (swizzled reads; row&15 == col on both tiles) ----
#pragma unroll
    for (int k = 0; k < 4; ++k) {
        int cbyte = (k * 64 + quad * 16) ^ (col << 4);
        bf16x8 af = *(const bf16x8*)&al_lds[(w * 16 + col) * 128 + (cbyte >> 1)];
#pragma unroll
        for (int ot = 0; ot < 8; ++ot) {
            bf16x8 bfv = *(const bf16x8*)&hT_lds[(ot * 16 + col) * 128 + (cbyte >> 1)];
            acc[ot] = __builtin_amdgcn_mfma_f32_16x16x32_bf16(af, bfv, acc[ot], 0, 0, 0);
        }
    }
    __syncthreads();   // MFMA reads done; LDS free for next phase A/B
}

template <bool WRITE_ALPHA>
__global__ __launch_bounds__(256) void k_attn_mfma(const int* __restrict__ adj,
                                                   const float* __restrict__ s_in,
                                                   const float* __restrict__ d_in_,
                                                   const float* __restrict__ M_in,
                                                   const float* __restrict__ Li_in,
                                                   const unsigned short* __restrict__ hT,
                                                   float* __restrict__ out_scr,
                                                   float* __restrict__ alpha_out) {
    __shared__ unsigned short al_lds[64 * 128];    // XOR-swizzled, no pad
    __shared__ unsigned short hT_lds[128 * 128];   // XOR-swizzled, no pad
    __shared__ float srow[64], Mrow[64], Lirow[64];
    int tid = threadIdx.x;
    // XCD-aware bijective swizzle (512 blocks % 8 XCDs == 0): XCD x owns
    // bids [x*64, (x+1)*64) == bh {2x, 2x+1} -> hT/adj tiles L2-resident.
    int bid = (int)(blockIdx.x & 7) * 64 + (int)(blockIdx.x >> 3);
    int bh = bid >> 5;
    int nb = (bid & 31) * 64;
    int b = bh >> 2;

    if (tid < 64) {
        srow[tid]  = s_in[bh * NN + nb + tid];
        Mrow[tid]  = M_in[bh * NN + nb + tid];
        Lirow[tid] = Li_in[bh * NN + nb + tid];
    }

    // phase-A mapping: 8 passes; pass p: row = p*8 + ar0, float-col = ac4..+3
    int ar0 = tid >> 5;                 // 0..7
    int ac4 = (tid & 31) * 4;           // 0..124
    const int* adj_base = adj + ((size_t)b * NN + nb + ar0) * NN + ac4;
    float* alpha_base = WRITE_ALPHA
        ? alpha_out + ((size_t)bh * NN + nb + ar0) * NN + ac4 : nullptr;
    const float* dg = d_in_ + (size_t)bh * NN;     // L2-hot 8 KB row
    // phase-B mapping: 16 lanes x 16B = 256B contiguous per o-row
    int hrow0 = tid >> 4;               // 0..15
    int hcolu = (tid & 15) * 8;         // ushort col 0..120
    const unsigned short* hbase = hT + ((size_t)bh * DD + hrow0) * NN + hcolu;
    int hbyte = (hcolu * 2) ^ (hrow0 << 4);
    // phase-C mapping: wave/lane
    int l = tid & 63, w = tid >> 6, col = l & 15, quad = l >> 4;

    f32x4 acc[8];
#pragma unroll
    for (int ot = 0; ot < 8; ++ot) acc[ot] = (f32x4){0.f, 0.f, 0.f, 0.f};

    TileRegs R0, R1;
    attn_load_tile(0, adj_base, dg, ac4, hbase, R0);
    __syncthreads();   // srow/Mrow/Lirow visible

    for (int mb = 0; mb < NN; mb += 256) {
        attn_tile_body<WRITE_ALPHA>(mb, R0, R1, adj_base, dg, ac4, hbase,
                                    al_lds, hT_lds, srow, Mrow, Lirow,
                                    alpha_base, ar0, hrow0, hbyte,
                                    w, col, quad, acc);
        attn_tile_body<WRITE_ALPHA>(mb + 128, R1, R0, adj_base, dg, ac4, hbase,
                                    al_lds, hT_lds, srow, Mrow, Lirow,
                                    alpha_base, ar0, hrow0, hbyte,
                                    w, col, quad, acc);
    }
    // epilogue: C/D layout col=lane&15, row=quad*4+reg
#pragma unroll
    for (int ot = 0; ot < 8; ++ot)
#pragma unroll
        for (int r = 0; r < 4; ++r)
            out_scr[((size_t)bh * NN + nb + w * 16 + quad * 4 + r) * DD + ot * 16 + col] =
                acc[ot][r];
}

// ---------------------------------------------------------------------------
// Kernel 4: output[b,n,o] = concat_h(out_scr) @ Wp + bias, fp32 store.
// ---------------------------------------------------------------------------
__global__ __launch_bounds__(256) void k_proj(const float* __restrict__ out_scr,
                                              const float* __restrict__ Wp,
                                              const float* __restrict__ bias,
                                              float* __restrict__ out) {
    __shared__ float cs[16 * 512];
    int tid = threadIdx.x;
    int b  = blockIdx.x / (NN / 16);
    int nb = (blockIdx.x % (NN / 16)) * 16;
    for (int idx = tid; idx < 16 * 512; idx += 256) {
        int r = idx >> 9, c = idx & 511;
        int hh = c >> 7, oo = c & 127;
        cs[idx] = out_scr[((size_t)(b * HH + hh) * NN + nb + r) * DD + oo];
    }
    __syncthreads();
    int o = tid & 63, rg = tid >> 6;        // 4 row-groups x 4 rows
    float bv0 = bias[o], bv1 = bias[o + 64];
    float acc0[4], acc1[4];
#pragma unroll
    for (int j = 0; j < 4; ++j) { acc0[j] = bv0; acc1[j] = bv1; }
    for (int k = 0; k < 512; k += 4) {
        float w00 = Wp[(k + 0) * DD + o], w01 = Wp[(k + 0) * DD + o + 64];
        float w10 = Wp[(k + 1) * DD + o], w11 = Wp[(k + 1) * DD + o + 64];
        float w20 = Wp[(k + 2) * DD + o], w21 = Wp[(k + 2) * DD + o + 64];
        float w30 = Wp[(k + 3) * DD + o], w31 = Wp[(k + 3) * DD + o + 64];
#pragma unroll
        for (int j = 0; j < 4; ++j) {
            float4 cq = *(const float4*)&cs[(rg * 4 + j) * 512 + k];
            acc0[j] += cq.x * w00 + cq.y * w10 + cq.z * w20 + cq.w * w30;
            acc1[j] += cq.x * w01 + cq.y * w11 + cq.z * w21 + cq.w * w31;
        }
    }
#pragma unroll
    for (int j = 0; j < 4; ++j) {
        out[((size_t)b * NN + nb + rg * 4 + j) * DD + o]      = acc0[j];
        out[((size_t)b * NN + nb + rg * 4 + j) * DD + o + 64] = acc1[j];
    }
}

// ---------------------------------------------------------------------------
// Kernel 5 (fallback only): write final fp32 alpha over the (now-consumed)
// scratch. Used only when the workspace is too small to host hT/out_scr.
// ---------------------------------------------------------------------------
__global__ __launch_bounds__(256) void k_alpha(const int* __restrict__ adj,
                                               const float* __restrict__ s_in,
                                               const float* __restrict__ d_in_,
                                               const float* __restrict__ M_in,
                                               const float* __restrict__ Li_in,
                                               float* __restrict__ alpha_out) {
    int tid = threadIdx.x;
    int b = blockIdx.x / NN, n = blockIdx.x % NN;
    float sv[4], Mv[4], Lv[4];
#pragma unroll
    for (int h = 0; h < 4; ++h) {
        sv[h] = s_in[(b * HH + h) * NN + n];
        Mv[h] = M_in[(b * HH + h) * NN + n];
        Lv[h] = Li_in[(b * HH + h) * NN + n];
    }
    const int* arow = adj + ((size_t)b * NN + n) * NN;
    for (int m = tid; m < NN; m += 256) {
        int av = arow[m];
#pragma unroll
        for (int h = 0; h < 4; ++h) {
            float val = 0.f;
            if (av != 0) {
                float t = sv[h] + d_in_[(b * HH + h) * NN + m];
                float v = t > 0.f ? t : 0.2f * t;
                val = exp2f((v - Mv[h]) * LOG2E) * Lv[h];
            }
            alpha_out[((size_t)(b * HH + h) * NN + n) * NN + m] = val;
        }
    }
}

// ---------------------------------------------------------------------------
extern "C" void kernel_launch(void* const* d_in, const int* in_sizes, int n_in,
                              void* d_out, int out_size, void* d_ws, size_t ws_size,
                              hipStream_t stream) {
    const float* x    = (const float*)d_in[0];
    const int*   adj  = (const int*)d_in[1];
    const float* W    = (const float*)d_in[2];
    const float* a    = (const float*)d_in[3];
    const float* Wp   = (const float*)d_in[4];
    const float* bias = (const float*)d_in[5];

    float* out       = (float*)d_out;
    float* alpha_out = out + (size_t)BB * NN * DD;

    // Stats always live in the workspace head (528 KB).
    float* ws  = (float*)d_ws;
    float* wsv = ws;
    float* wdv = wsv + HH * DD;
    float* s_  = wdv + HH * DD;
    float* d_  = s_ + (size_t)BB * HH * NN;
    float* M_  = d_ + (size_t)BB * HH * NN;
    float* Li_ = M_ + (size_t)BB * HH * NN;

    const size_t stats_bytes = (2 * HH * DD + 4 * (size_t)BB * HH * NN) * sizeof(float);
    const size_t hT_bytes    = (size_t)BB * HH * NN * DD * sizeof(unsigned short);  // 8.39 MB
    const size_t scr_bytes   = (size_t)BB * HH * NN * DD * sizeof(float);           // 16.8 MB
    const bool fused = ws_size >= stats_bytes + hT_bytes + scr_bytes;

    unsigned short* hT;
    float* out_scr;
    if (fused) {
        hT      = (unsigned short*)((char*)d_ws + stats_bytes);
        out_scr = (float*)((char*)hT + hT_bytes);
    } else {
        hT      = (unsigned short*)alpha_out;
        out_scr = alpha_out + (size_t)BB * HH * NN * DD;
    }

    k_wvec<<<HH, 128, 0, stream>>>(W, a, wsv, wdv);
    k_h<<<BB * HH * (NN / 32), 256, 0, stream>>>(x, W, wsv, wdv, hT, s_, d_);
    k_stats<<<BB * NN, 256, 0, stream>>>(adj, s_, d_, M_, Li_);
    if (fused) {
        k_attn_mfma<true><<<BB * HH * (NN / 64), 256, 0, stream>>>(adj, s_, d_, M_, Li_,
                                                                   hT, out_scr, alpha_out);
        k_proj<<<BB * (NN / 16), 256, 0, stream>>>(out_scr, Wp, bias, out);
    } else {
        k_attn_mfma<false><<<BB * HH * (NN / 64), 256, 0, stream>>>(adj, s_, d_, M_, Li_,
                                                                    hT, out_scr, alpha_out);
        k_proj<<<BB * (NN / 16), 256, 0, stream>>>(out_scr, Wp, bias, out);
        k_alpha<<<BB * NN, 256, 0, stream>>>(adj, s_, d_, M_, Li_, alpha_out);
    }
}

// Round 7
// 454.922 us; speedup vs baseline: 1.3225x; 1.0000x over previous
//
#include <hip/hip_runtime.h>
#include <hip/hip_bf16.h>

#define BB 4
#define NN 2048
#define DD 128
#define HH 4
#define LOG2E 1.4426950408889634f
#define NEG_BIG (-1e30f)

typedef __attribute__((ext_vector_type(8))) short bf16x8;   // 8 bf16 in 4 VGPRs
typedef __attribute__((ext_vector_type(4))) short bf16x4;   // 4 bf16 in 2 VGPRs
typedef __attribute__((ext_vector_type(4))) float f32x4;    // MFMA accumulator

__device__ __forceinline__ unsigned short f2bf(float f) {
    union { float f; unsigned int u; } v; v.f = f;
    unsigned int r = v.u + 0x7FFF + ((v.u >> 16) & 1);      // round-nearest-even
    return (unsigned short)(r >> 16);
}

// ---------------------------------------------------------------------------
// Kernel A: wsv[h][i] = sum_o W[h,i,o]*a[h,o]; wdv likewise with a[h,D+o].
// ---------------------------------------------------------------------------
__global__ __launch_bounds__(128) void k_wvec(const float* __restrict__ W,
                                              const float* __restrict__ a,
                                              float* __restrict__ wsv,
                                              float* __restrict__ wdv) {
    int h = blockIdx.x;
    int i = threadIdx.x;
    const float* Wr  = W + (h * DD + i) * DD;
    const float* as_ = a + h * 2 * DD;
    const float* ad_ = as_ + DD;
    float s = 0.f, d = 0.f;
    for (int o = 0; o < DD; ++o) {
        float w = Wr[o];
        s += w * as_[o];
        d += w * ad_[o];
    }
    wsv[h * DD + i] = s;
    wdv[h * DD + i] = d;
}

// ---------------------------------------------------------------------------
// Kernel H (fuses old k_sd): h[b,h,n,o] = sum_i x[b,n,i]*W[h,i,o],
// stored TRANSPOSED bf16 hT[bh][o][n]; plus s,d row dots (x staged anyway).
// ---------------------------------------------------------------------------
__global__ __launch_bounds__(256) void k_h(const float* __restrict__ x,
                                           const float* __restrict__ W,
                                           const float* __restrict__ wsv,
                                           const float* __restrict__ wdv,
                                           unsigned short* __restrict__ hT,
                                           float* __restrict__ s_out,
                                           float* __restrict__ d_out_) {
    __shared__ float xs[32 * 132];
    int tid = threadIdx.x;
    int bh = blockIdx.x / (NN / 32);
    int nb = (blockIdx.x % (NN / 32)) * 32;
    int b = bh >> 2, h = bh & 3;
    for (int idx = tid; idx < 32 * 128; idx += 256) {
        int r = idx >> 7, c = idx & 127;
        xs[r * 132 + c] = x[((size_t)b * NN + nb + r) * DD + c];
    }
    __syncthreads();
    int o = tid & 127, rh = tid >> 7;   // rh in {0,1}: 16 n-rows each
    float acc[16];
#pragma unroll
    for (int j = 0; j < 16; ++j) acc[j] = 0.f;
    const float* Wc = W + (size_t)h * DD * DD + o;
    for (int i = 0; i < DD; i += 4) {
        float w0 = Wc[(i + 0) * DD];
        float w1 = Wc[(i + 1) * DD];
        float w2 = Wc[(i + 2) * DD];
        float w3 = Wc[(i + 3) * DD];
#pragma unroll
        for (int j = 0; j < 16; ++j) {
            float4 xq = *(const float4*)&xs[(rh * 16 + j) * 132 + i];
            acc[j] += xq.x * w0 + xq.y * w1 + xq.z * w2 + xq.w * w3;
        }
    }
    bf16x8 p0, p1;
#pragma unroll
    for (int j = 0; j < 8; ++j) { p0[j] = (short)f2bf(acc[j]); p1[j] = (short)f2bf(acc[8 + j]); }
    unsigned short* dst = hT + ((size_t)bh * DD + o) * NN + nb + rh * 16;
    *(bf16x8*)dst = p0;
    *(bf16x8*)(dst + 8) = p1;

    // --- fused k_sd: s,d for these 32 rows (8 threads/row, 16-elem segments)
    {
        int r = tid >> 3, seg = (tid & 7) * 16;
        const float* wsp = wsv + h * DD + seg;
        const float* wdp = wdv + h * DD + seg;
        float sv = 0.f, dv = 0.f;
#pragma unroll
        for (int j = 0; j < 16; j += 4) {
            float4 xq = *(const float4*)&xs[r * 132 + seg + j];
            float4 wq = *(const float4*)(wsp + j);
            float4 vq = *(const float4*)(wdp + j);
            sv += xq.x * wq.x + xq.y * wq.y + xq.z * wq.z + xq.w * wq.w;
            dv += xq.x * vq.x + xq.y * vq.y + xq.z * vq.z + xq.w * vq.w;
        }
#pragma unroll
        for (int off = 1; off < 8; off <<= 1) {
            sv += __shfl_xor(sv, off, 64);
            dv += __shfl_xor(dv, off, 64);
        }
        if ((tid & 7) == 0) {
            s_out[(b * HH + h) * NN + nb + r]  = sv;
            d_out_[(b * HH + h) * NN + nb + r] = dv;
        }
    }
}

// ---------------------------------------------------------------------------
// Kernel DMAX: dmax[bh] = max_m d[bh,m]. Stabilizer source: since lrelu is
// monotone, lrelu(s_n + dmax) >= every logit of row n — a valid softmax
// stabilizer without the true per-row max. 16 blocks, ~2 us.
// ---------------------------------------------------------------------------
__global__ __launch_bounds__(256) void k_dmax(const float* __restrict__ d_,
                                              float* __restrict__ dmax_) {
    __shared__ float red[4];
    int bh = blockIdx.x, tid = threadIdx.x;
    const float4* dp = (const float4*)(d_ + (size_t)bh * NN);
    float4 v0 = dp[tid];
    float4 v1 = dp[256 + tid];
    float m = fmaxf(fmaxf(fmaxf(v0.x, v0.y), fmaxf(v0.z, v0.w)),
                    fmaxf(fmaxf(v1.x, v1.y), fmaxf(v1.z, v1.w)));
#pragma unroll
    for (int off = 32; off >= 1; off >>= 1)
        m = fmaxf(m, __shfl_xor(m, off, 64));
    if ((tid & 63) == 0) red[tid >> 6] = m;
    __syncthreads();
    if (tid == 0)
        dmax_[bh] = fmaxf(fmaxf(red[0], red[1]), fmaxf(red[2], red[3]));
}

// ---------------------------------------------------------------------------
// Kernel 3 (MFMA, self-normalizing — k_stats ELIMINATED):
// pass 1: sweep m-tiles computing E = exp(lrelu(s+d) - M) over valid m,
//         accumulate row-sums L in registers (32-lane shuffle reduce).
//         M = lrelu(s_n + dmax_bh) — valid upper bound, per-row constant.
// pass 2: pipelined alpha->LDS->MFMA loop using in-register M, Li.
// adj is read twice but the 2nd pass hits L3 (67 MB << 256 MB).
// ---------------------------------------------------------------------------
struct TileRegs {
    int4   a4[8];
    float4 d4;
    bf16x8 hv[8];
};
struct P1Regs {
    int4   a4[8];
    float4 d4;
};

__device__ __forceinline__ void attn_load_tile(int mb, const int* adj_base,
                                               const float* dg, int ac4,
                                               const unsigned short* hbase,
                                               TileRegs& R) {
#pragma unroll
    for (int p = 0; p < 8; ++p)
        R.a4[p] = *(const int4*)(adj_base + (size_t)(p * 8) * NN + mb);
    R.d4 = *(const float4*)(dg + mb + ac4);
#pragma unroll
    for (int q = 0; q < 8; ++q)
        R.hv[q] = *(const bf16x8*)(hbase + (size_t)(q * 16) * NN + mb);
}

__device__ __forceinline__ void p1_load(int mb, const int* adj_base,
                                        const float* dg, int ac4, P1Regs& R) {
#pragma unroll
    for (int p = 0; p < 8; ++p)
        R.a4[p] = *(const int4*)(adj_base + (size_t)(p * 8) * NN + mb);
    R.d4 = *(const float4*)(dg + mb + ac4);
}

__device__ __forceinline__ void p1_accum(const P1Regs& R, const float (&sreg)[8],
                                         const float (&Mreg)[8], float (&Lp)[8]) {
#pragma unroll
    for (int p = 0; p < 8; ++p) {
        float sn = sreg[p], Mn = Mreg[p];
        float t0 = sn + R.d4.x, t1 = sn + R.d4.y;
        float t2 = sn + R.d4.z, t3 = sn + R.d4.w;
        float v0 = t0 > 0.f ? t0 : 0.2f * t0;
        float v1 = t1 > 0.f ? t1 : 0.2f * t1;
        float v2 = t2 > 0.f ? t2 : 0.2f * t2;
        float v3 = t3 > 0.f ? t3 : 0.2f * t3;
        float e0 = (R.a4[p].x != 0) ? exp2f((v0 - Mn) * LOG2E) : 0.f;
        float e1 = (R.a4[p].y != 0) ? exp2f((v1 - Mn) * LOG2E) : 0.f;
        float e2 = (R.a4[p].z != 0) ? exp2f((v2 - Mn) * LOG2E) : 0.f;
        float e3 = (R.a4[p].w != 0) ? exp2f((v3 - Mn) * LOG2E) : 0.f;
        Lp[p] += (e0 + e1) + (e2 + e3);
    }
}

template <bool WRITE_ALPHA>
__device__ __forceinline__ void attn_tile_body(
    int mb, TileRegs& cur, TileRegs& nxt,
    const int* adj_base, const float* dg, int ac4,
    const unsigned short* hbase,
    unsigned short* al_lds, unsigned short* hT_lds,
    const float (&sreg)[8], const float (&Mreg)[8], const float (&Lin)[8],
    float* alpha_base, int ar0, int hrow0, int hbyte,
    int w, int col, int quad, f32x4 (&acc)[8])
{
    // ---- phase A: alpha (bf16 -> LDS swizzled; fp32 -> coalesced store) ----
#pragma unroll
    for (int p = 0; p < 8; ++p) {
        int row = p * 8 + ar0;
        float sn = sreg[p], Mn = Mreg[p], Li = Lin[p];
        float t0 = sn + cur.d4.x, t1 = sn + cur.d4.y;
        float t2 = sn + cur.d4.z, t3 = sn + cur.d4.w;
        float v0 = t0 > 0.f ? t0 : 0.2f * t0;
        float v1 = t1 > 0.f ? t1 : 0.2f * t1;
        float v2 = t2 > 0.f ? t2 : 0.2f * t2;
        float v3 = t3 > 0.f ? t3 : 0.2f * t3;
        float e0 = (cur.a4[p].x != 0) ? exp2f((v0 - Mn) * LOG2E) * Li : 0.f;
        float e1 = (cur.a4[p].y != 0) ? exp2f((v1 - Mn) * LOG2E) * Li : 0.f;
        float e2 = (cur.a4[p].z != 0) ? exp2f((v2 - Mn) * LOG2E) * Li : 0.f;
        float e3 = (cur.a4[p].w != 0) ? exp2f((v3 - Mn) * LOG2E) * Li : 0.f;
        bf16x4 pk;
        pk[0] = (short)f2bf(e0); pk[1] = (short)f2bf(e1);
        pk[2] = (short)f2bf(e2); pk[3] = (short)f2bf(e3);
        int abyte = (ac4 * 2) ^ ((row & 15) << 4);      // swizzled byte-in-row
        *(bf16x4*)&al_lds[row * 128 + (abyte >> 1)] = pk;
        if (WRITE_ALPHA) {
            float4 ev; ev.x = e0; ev.y = e1; ev.z = e2; ev.w = e3;
            *(float4*)(alpha_base + (size_t)(p * 8) * NN + mb) = ev;
        }
    }
    // ---- phase B: stage hT chunk [128 o][128 m], swizzled ----
#pragma unroll
    for (int q = 0; q < 8; ++q)
        *(bf16x8*)&hT_lds[(q * 16 + hrow0) * 128 + (hbyte >> 1)] = cur.hv[q];

    // ---- prefetch next tile into nxt (in flight across barrier + MFMA) ----
    attn_load_tile((mb + 128) & (NN - 1), adj_base, dg, ac4, hbase, nxt);

    __syncthreads();
    // ---- phase C: MFMA (swizzled reads; row&15 == col on both tiles) ----
#pragma unroll
    for (int k = 0; k < 4; ++k) {
        int cbyte = (k * 64 + quad * 16) ^ (col << 4);
        bf16x8 af = *(const bf16x8*)&al_lds[(w * 16 + col) * 128 + (cbyte >> 1)];
#pragma unroll
        for (int ot = 0; ot < 8; ++ot) {
            bf16x8 bfv = *(const bf16x8*)&hT_lds[(ot * 16 + col) * 128 + (cbyte >> 1)];
            acc[ot] = __builtin_amdgcn_mfma_f32_16x16x32_bf16(af, bfv, acc[ot], 0, 0, 0);
        }
    }
    __syncthreads();   // MFMA reads done; LDS free for next phase A/B
}

template <bool WRITE_ALPHA>
__global__ __launch_bounds__(256) void k_attn_mfma(const int* __restrict__ adj,
                                                   const float* __restrict__ s_in,
                                                   const float* __restrict__ d_in_,
                                                   const float* __restrict__ dmax_,
                                                   const unsigned short* __restrict__ hT,
                                                   float* __restrict__ out_scr,
                                                   float* __restrict__ alpha_out,
                                                   float* __restrict__ Li_out) {
    __shared__ unsigned short al_lds[64 * 128];    // XOR-swizzled, no pad
    __shared__ unsigned short hT_lds[128 * 128];   // XOR-swizzled, no pad
    int tid = threadIdx.x;
    // XCD-aware bijective swizzle (512 blocks % 8 XCDs == 0).
    int bid = (int)(blockIdx.x & 7) * 64 + (int)(blockIdx.x >> 3);
    int bh = bid >> 5;
    int nb = (bid & 31) * 64;
    int b = bh >> 2;

    // phase-A mapping: 8 passes; pass p: row = p*8 + ar0, float-col = ac4..+3
    int ar0 = tid >> 5;                 // 0..7
    int ac4 = (tid & 31) * 4;           // 0..124
    const int* adj_base = adj + ((size_t)b * NN + nb + ar0) * NN + ac4;
    float* alpha_base = WRITE_ALPHA
        ? alpha_out + ((size_t)bh * NN + nb + ar0) * NN + ac4 : nullptr;
    const float* dg = d_in_ + (size_t)bh * NN;     // L2-hot 8 KB row

    // per-row stabilizer + s (in regs; rows p*8+ar0, shared by 32-lane group)
    float dmx = dmax_[bh];
    float sreg[8], Mreg[8];
#pragma unroll
    for (int p = 0; p < 8; ++p) {
        sreg[p] = s_in[bh * NN + nb + p * 8 + ar0];
        float t = sreg[p] + dmx;
        Mreg[p] = t > 0.f ? t : 0.2f * t;
    }

    // ---------------- pass 1: row sums L (register-resident) ----------------
    float Lp[8];
#pragma unroll
    for (int p = 0; p < 8; ++p) Lp[p] = 0.f;
    {
        P1Regs A0, A1;
        p1_load(0, adj_base, dg, ac4, A0);
        for (int mb = 0; mb < NN; mb += 256) {
            p1_load(mb + 128, adj_base, dg, ac4, A1);
            p1_accum(A0, sreg, Mreg, Lp);
            p1_load((mb + 256) & (NN - 1), adj_base, dg, ac4, A0);
            p1_accum(A1, sreg, Mreg, Lp);
        }
    }
    // reduce across the 32 lanes sharing each row (xor stays in 32-halves)
#pragma unroll
    for (int off = 16; off >= 1; off >>= 1)
#pragma unroll
        for (int p = 0; p < 8; ++p)
            Lp[p] += __shfl_xor(Lp[p], off, 64);
    float Lin[8];
#pragma unroll
    for (int p = 0; p < 8; ++p) Lin[p] = Lp[p] > 0.f ? 1.f / Lp[p] : 0.f;
    if (!WRITE_ALPHA && (tid & 31) == 0) {
#pragma unroll
        for (int p = 0; p < 8; ++p)
            Li_out[bh * NN + nb + p * 8 + ar0] = Lin[p];
    }

    // ---------------- pass 2: alpha -> LDS -> MFMA (pipelined) --------------
    // phase-B mapping: 16 lanes x 16B = 256B contiguous per o-row
    int hrow0 = tid >> 4;               // 0..15
    int hcolu = (tid & 15) * 8;         // ushort col 0..120
    const unsigned short* hbase = hT + ((size_t)bh * DD + hrow0) * NN + hcolu;
    int hbyte = (hcolu * 2) ^ (hrow0 << 4);
    // phase-C mapping: wave/lane
    int l = tid & 63, w = tid >> 6, col = l & 15, quad = l >> 4;

    f32x4 acc[8];
#pragma unroll
    for (int ot = 0; ot < 8; ++ot) acc[ot] = (f32x4){0.f, 0.f, 0.f, 0.f};

    TileRegs R0, R1;
    attn_load_tile(0, adj_base, dg, ac4, hbase, R0);

    for (int mb = 0; mb < NN; mb += 256) {
        attn_tile_body<WRITE_ALPHA>(mb, R0, R1, adj_base, dg, ac4, hbase,
                                    al_lds, hT_lds, sreg, Mreg, Lin,
                                    alpha_base, ar0, hrow0, hbyte,
                                    w, col, quad, acc);
        attn_tile_body<WRITE_ALPHA>(mb + 128, R1, R0, adj_base, dg, ac4, hbase,
                                    al_lds, hT_lds, sreg, Mreg, Lin,
                                    alpha_base, ar0, hrow0, hbyte,
                                    w, col, quad, acc);
    }
    // epilogue: C/D layout col=lane&15, row=quad*4+reg
#pragma unroll
    for (int ot = 0; ot < 8; ++ot)
#pragma unroll
        for (int r = 0; r < 4; ++r)
            out_scr[((size_t)bh * NN + nb + w * 16 + quad * 4 + r) * DD + ot * 16 + col] =
                acc[ot][r];
}

// ---------------------------------------------------------------------------
// Kernel 4: output[b,n,o] = concat_h(out_scr) @ Wp + bias, fp32 store.
// ---------------------------------------------------------------------------
__global__ __launch_bounds__(256) void k_proj(const float* __restrict__ out_scr,
                                              const float* __restrict__ Wp,
                                              const float* __restrict__ bias,
                                              float* __restrict__ out) {
    __shared__ float cs[16 * 512];
    int tid = threadIdx.x;
    int b  = blockIdx.x / (NN / 16);
    int nb = (blockIdx.x % (NN / 16)) * 16;
    for (int idx = tid; idx < 16 * 512; idx += 256) {
        int r = idx >> 9, c = idx & 511;
        int hh = c >> 7, oo = c & 127;
        cs[idx] = out_scr[((size_t)(b * HH + hh) * NN + nb + r) * DD + oo];
    }
    __syncthreads();
    int o = tid & 63, rg = tid >> 6;        // 4 row-groups x 4 rows
    float bv0 = bias[o], bv1 = bias[o + 64];
    float acc0[4], acc1[4];
#pragma unroll
    for (int j = 0; j < 4; ++j) { acc0[j] = bv0; acc1[j] = bv1; }
    for (int k = 0; k < 512; k += 4) {
        float w00 = Wp[(k + 0) * DD + o], w01 = Wp[(k + 0) * DD + o + 64];
        float w10 = Wp[(k + 1) * DD + o], w11 = Wp[(k + 1) * DD + o + 64];
        float w20 = Wp[(k + 2) * DD + o], w21 = Wp[(k + 2) * DD + o + 64];
        float w30 = Wp[(k + 3) * DD + o], w31 = Wp[(k + 3) * DD + o + 64];
#pragma unroll
        for (int j = 0; j < 4; ++j) {
            float4 cq = *(const float4*)&cs[(rg * 4 + j) * 512 + k];
            acc0[j] += cq.x * w00 + cq.y * w10 + cq.z * w20 + cq.w * w30;
            acc1[j] += cq.x * w01 + cq.y * w11 + cq.z * w21 + cq.w * w31;
        }
    }
#pragma unroll
    for (int j = 0; j < 4; ++j) {
        out[((size_t)b * NN + nb + rg * 4 + j) * DD + o]      = acc0[j];
        out[((size_t)b * NN + nb + rg * 4 + j) * DD + o + 64] = acc1[j];
    }
}

// ---------------------------------------------------------------------------
// Kernel 5 (fallback only): write final fp32 alpha over the (now-consumed)
// scratch. M recomputed from s+dmax; Li from the array k_attn stored.
// ---------------------------------------------------------------------------
__global__ __launch_bounds__(256) void k_alpha(const int* __restrict__ adj,
                                               const float* __restrict__ s_in,
                                               const float* __restrict__ d_in_,
                                               const float* __restrict__ dmax_,
                                               const float* __restrict__ Li_in,
                                               float* __restrict__ alpha_out) {
    int tid = threadIdx.x;
    int b = blockIdx.x / NN, n = blockIdx.x % NN;
    float sv[4], Mv[4], Lv[4];
#pragma unroll
    for (int h = 0; h < 4; ++h) {
        sv[h] = s_in[(b * HH + h) * NN + n];
        float t = sv[h] + dmax_[b * HH + h];
        Mv[h] = t > 0.f ? t : 0.2f * t;
        Lv[h] = Li_in[(b * HH + h) * NN + n];
    }
    const int* arow = adj + ((size_t)b * NN + n) * NN;
    for (int m = tid; m < NN; m += 256) {
        int av = arow[m];
#pragma unroll
        for (int h = 0; h < 4; ++h) {
            float val = 0.f;
            if (av != 0) {
                float t = sv[h] + d_in_[(b * HH + h) * NN + m];
                float v = t > 0.f ? t : 0.2f * t;
                val = exp2f((v - Mv[h]) * LOG2E) * Lv[h];
            }
            alpha_out[((size_t)(b * HH + h) * NN + n) * NN + m] = val;
        }
    }
}

// ---------------------------------------------------------------------------
extern "C" void kernel_launch(void* const* d_in, const int* in_sizes, int n_in,
                              void* d_out, int out_size, void* d_ws, size_t ws_size,
                              hipStream_t stream) {
    const float* x    = (const float*)d_in[0];
    const int*   adj  = (const int*)d_in[1];
    const float* W    = (const float*)d_in[2];
    const float* a    = (const float*)d_in[3];
    const float* Wp   = (const float*)d_in[4];
    const float* bias = (const float*)d_in[5];

    float* out       = (float*)d_out;
    float* alpha_out = out + (size_t)BB * NN * DD;

    // Stats in the workspace head.
    float* ws   = (float*)d_ws;
    float* wsv  = ws;
    float* wdv  = wsv + HH * DD;
    float* s_   = wdv + HH * DD;
    float* d_   = s_ + (size_t)BB * HH * NN;
    float* Li_  = d_ + (size_t)BB * HH * NN;
    float* dmax_= Li_ + (size_t)BB * HH * NN;

    const size_t stats_bytes = (2 * HH * DD + 3 * (size_t)BB * HH * NN + 16) * sizeof(float);
    const size_t hT_bytes    = (size_t)BB * HH * NN * DD * sizeof(unsigned short);  // 8.39 MB
    const size_t scr_bytes   = (size_t)BB * HH * NN * DD * sizeof(float);           // 16.8 MB
    const bool fused = ws_size >= stats_bytes + hT_bytes + scr_bytes;

    unsigned short* hT;
    float* out_scr;
    if (fused) {
        hT      = (unsigned short*)((char*)d_ws + stats_bytes);
        out_scr = (float*)((char*)hT + hT_bytes);
    } else {
        hT      = (unsigned short*)alpha_out;
        out_scr = alpha_out + (size_t)BB * HH * NN * DD;
    }

    k_wvec<<<HH, 128, 0, stream>>>(W, a, wsv, wdv);
    k_h<<<BB * HH * (NN / 32), 256, 0, stream>>>(x, W, wsv, wdv, hT, s_, d_);
    k_dmax<<<BB * HH, 256, 0, stream>>>(d_, dmax_);
    if (fused) {
        k_attn_mfma<true><<<BB * HH * (NN / 64), 256, 0, stream>>>(adj, s_, d_, dmax_,
                                                                   hT, out_scr, alpha_out, Li_);
        k_proj<<<BB * (NN / 16), 256, 0, stream>>>(out_scr, Wp, bias, out);
    } else {
        k_attn_mfma<false><<<BB * HH * (NN / 64), 256, 0, stream>>>(adj, s_, d_, dmax_,
                                                                    hT, out_scr, alpha_out, Li_);
        k_proj<<<BB * (NN / 16), 256, 0, stream>>>(out_scr, Wp, bias, out);
        k_alpha<<<BB * NN, 256, 0, stream>>>(adj, s_, d_, dmax_, Li_, alpha_out);
    }
}

// Round 8
// 444.725 us; speedup vs baseline: 1.3528x; 1.0229x over previous
//
#include <hip/hip_runtime.h>
#include <hip/hip_bf16.h>

#define BB 4
#define NN 2048
#define DD 128
#define HH 4
#define LOG2E 1.4426950408889634f
#define NEG_BIG (-1e30f)

typedef __attribute__((ext_vector_type(8))) short bf16x8;     // 8 bf16 in 4 VGPRs
typedef __attribute__((ext_vector_type(4))) short bf16x4;     // 4 bf16 in 2 VGPRs
typedef __attribute__((ext_vector_type(4))) float f32x4;      // MFMA accumulator
typedef __attribute__((ext_vector_type(8))) _Float16 f16x8;   // 8 fp16 in 4 VGPRs
typedef __attribute__((ext_vector_type(4))) _Float16 f16x4;   // 4 fp16 in 2 VGPRs

__device__ __forceinline__ unsigned short f2bf(float f) {
    union { float f; unsigned int u; } v; v.f = f;
    unsigned int r = v.u + 0x7FFF + ((v.u >> 16) & 1);        // round-nearest-even
    return (unsigned short)(r >> 16);
}

// ---------------------------------------------------------------------------
// Kernel PREP: wsv/wdv (score vectors) + WT16[h][o][i] = fp16 transpose of W.
// ---------------------------------------------------------------------------
__global__ __launch_bounds__(128) void k_prep(const float* __restrict__ W,
                                              const float* __restrict__ a,
                                              float* __restrict__ wsv,
                                              float* __restrict__ wdv,
                                              _Float16* __restrict__ WT16) {
    int h = blockIdx.x;
    int i = threadIdx.x;
    const float* Wr  = W + (h * DD + i) * DD;
    const float* as_ = a + h * 2 * DD;
    const float* ad_ = as_ + DD;
    float s = 0.f, d = 0.f;
    for (int o = 0; o < DD; ++o) {
        float w = Wr[o];
        s += w * as_[o];
        d += w * ad_[o];
        WT16[((size_t)h * DD + o) * DD + i] = (_Float16)w;   // coalesced over i
    }
    wsv[h * DD + i] = s;
    wdv[h * DD + i] = d;
}

// ---------------------------------------------------------------------------
// Kernel B (restored from R2, proven): s[b,h,n] = x[b,n,:].wsv[h]; d likewise.
// fp32 throughout — s,d feed exponents, keep exact.
// ---------------------------------------------------------------------------
__global__ __launch_bounds__(256) void k_sd(const float* __restrict__ x,
                                            const float* __restrict__ wsv,
                                            const float* __restrict__ wdv,
                                            float* __restrict__ s_out,
                                            float* __restrict__ d_out_) {
    __shared__ float xs[64 * 129];
    __shared__ float ws[4 * 129], wd[4 * 129];
    int tid = threadIdx.x;
    int b  = blockIdx.x / (NN / 64);
    int nb = (blockIdx.x % (NN / 64)) * 64;
    for (int idx = tid; idx < HH * DD; idx += 256) {
        ws[(idx >> 7) * 129 + (idx & 127)] = wsv[idx];
        wd[(idx >> 7) * 129 + (idx & 127)] = wdv[idx];
    }
    for (int idx = tid; idx < 64 * 128; idx += 256) {
        int r = idx >> 7, c = idx & 127;
        xs[r * 129 + c] = x[((size_t)b * NN + nb + r) * DD + c];
    }
    __syncthreads();
    int h = tid & 3, r = tid >> 2;
    float sv = 0.f, dv = 0.f;
#pragma unroll 8
    for (int i = 0; i < DD; ++i) {
        float xv = xs[r * 129 + i];
        sv += xv * ws[h * 129 + i];
        dv += xv * wd[h * 129 + i];
    }
    int n = nb + r;
    s_out[(b * HH + h) * NN + n] = sv;
    d_out_[(b * HH + h) * NN + n] = dv;
}

// ---------------------------------------------------------------------------
// Kernel H (MFMA rewrite): hT[bh][o][n] (bf16) = (W^T @ x^T) via fp16 MFMA.
// Old VALU version was LDS-issue-bound (~41 us); MFMA needs ~36 b128/wave.
// A = WT (o rows), B = x^T (n cols), both fp16 in XOR-swizzled LDS — same
// cbyte formula as the verified k_attn phase C. C row=o(quad*4+r), col=n.
// fp16 input rounding (~2^-11 rel) is below the bf16 store rounding (2^-9).
// ---------------------------------------------------------------------------
__global__ __launch_bounds__(256) void k_h_mfma(const float* __restrict__ x,
                                                const _Float16* __restrict__ WT16,
                                                unsigned short* __restrict__ hT) {
    __shared__ unsigned short wt_lds[128 * 128];   // fp16 bits, swizzled
    __shared__ unsigned short x_lds[64 * 128];     // fp16 bits, swizzled
    int tid = threadIdx.x;
    int bh = blockIdx.x >> 5;                      // NN/64 = 32 n-tiles
    int nb = (blockIdx.x & 31) * 64;
    int b = bh >> 2, h = bh & 3;

    // stage WT[h]: thread -> (o row, 64-i half); swizzle byte ^= (o&15)<<4
    {
        int o = tid >> 1, ihalf = (tid & 1) * 64;
        const _Float16* src = WT16 + ((size_t)h * DD + o) * DD + ihalf;
#pragma unroll
        for (int q = 0; q < 8; ++q) {
            f16x8 v = *(const f16x8*)(src + q * 8);
            int byte = ((ihalf + q * 8) * 2) ^ ((o & 15) << 4);
            *(f16x8*)&wt_lds[o * 128 + (byte >> 1)] = v;
        }
    }
    // stage x tile (fp32 -> fp16): thread -> (n row, 32-i segment)
    {
        int n = tid >> 2, iseg = (tid & 3) * 32;
        const float* src = x + ((size_t)b * NN + nb + n) * DD + iseg;
#pragma unroll
        for (int q = 0; q < 8; ++q) {
            float4 v = *(const float4*)(src + q * 4);
            f16x4 p;
            p[0] = (_Float16)v.x; p[1] = (_Float16)v.y;
            p[2] = (_Float16)v.z; p[3] = (_Float16)v.w;
            int byte = ((iseg + q * 4) * 2) ^ ((n & 15) << 4);
            *(f16x4*)&x_lds[n * 128 + (byte >> 1)] = p;
        }
    }
    __syncthreads();

    int l = tid & 63, w = tid >> 6, col = l & 15, quad = l >> 4;
    f32x4 acc[8];
#pragma unroll
    for (int ot = 0; ot < 8; ++ot) acc[ot] = (f32x4){0.f, 0.f, 0.f, 0.f};
#pragma unroll
    for (int k = 0; k < 4; ++k) {
        int cbyte = (k * 64 + quad * 16) ^ (col << 4);
        f16x8 bv = *(const f16x8*)&x_lds[(w * 16 + col) * 128 + (cbyte >> 1)];
#pragma unroll
        for (int ot = 0; ot < 8; ++ot) {
            f16x8 av = *(const f16x8*)&wt_lds[(ot * 16 + col) * 128 + (cbyte >> 1)];
            acc[ot] = __builtin_amdgcn_mfma_f32_16x16x32_f16(av, bv, acc[ot], 0, 0, 0);
        }
    }
    // epilogue: o = ot*16 + quad*4 + r, n = nb + w*16 + col
    unsigned short* base = hT + (size_t)bh * DD * NN;
#pragma unroll
    for (int ot = 0; ot < 8; ++ot)
#pragma unroll
        for (int r = 0; r < 4; ++r)
            base[(size_t)(ot * 16 + quad * 4 + r) * NN + nb + w * 16 + col] =
                f2bf(acc[ot][r]);
}

// ---------------------------------------------------------------------------
// Kernel DMAX: dmax[bh] = max_m d[bh,m] (valid stabilizer source).
// ---------------------------------------------------------------------------
__global__ __launch_bounds__(256) void k_dmax(const float* __restrict__ d_,
                                              float* __restrict__ dmax_) {
    __shared__ float red[4];
    int bh = blockIdx.x, tid = threadIdx.x;
    const float4* dp = (const float4*)(d_ + (size_t)bh * NN);
    float4 v0 = dp[tid];
    float4 v1 = dp[256 + tid];
    float m = fmaxf(fmaxf(fmaxf(v0.x, v0.y), fmaxf(v0.z, v0.w)),
                    fmaxf(fmaxf(v1.x, v1.y), fmaxf(v1.z, v1.w)));
#pragma unroll
    for (int off = 32; off >= 1; off >>= 1)
        m = fmaxf(m, __shfl_xor(m, off, 64));
    if ((tid & 63) == 0) red[tid >> 6] = m;
    __syncthreads();
    if (tid == 0)
        dmax_[bh] = fmaxf(fmaxf(red[0], red[1]), fmaxf(red[2], red[3]));
}

// ---------------------------------------------------------------------------
// Kernel 3 (MFMA attention). Round-7 reorder: __syncthreads drains vmcnt(0)
// [guide §5], so all VMEM must be issued EARLY enough that phase-A VALU
// (~1500 cyc of exp) covers it before the barrier drain:
//   top of iter: issue hv(t) [single-buffered] + adjD(t+1) [double-buffered]
//   phase A (exp from adjD(t) regs + alpha stores + al_lds) covers both
//   phase B writes hv(t) -> LDS (in-order vmcnt wait is free: hv are oldest)
//   barrier-1 drain: covered; MFMA; barrier-2 drain (alpha stores): covered.
// ---------------------------------------------------------------------------
struct AdjD {
    int4   a4[8];
    float4 d4;
};

__device__ __forceinline__ void adjd_load(int mb, const int* adj_base,
                                          const float* dg, int ac4, AdjD& R) {
#pragma unroll
    for (int p = 0; p < 8; ++p)
        R.a4[p] = *(const int4*)(adj_base + (size_t)(p * 8) * NN + mb);
    R.d4 = *(const float4*)(dg + mb + ac4);
}

__device__ __forceinline__ void p1_accum(const AdjD& R, const float (&sreg)[8],
                                         const float (&Mreg)[8], float (&Lp)[8]) {
#pragma unroll
    for (int p = 0; p < 8; ++p) {
        float sn = sreg[p], Mn = Mreg[p];
        float t0 = sn + R.d4.x, t1 = sn + R.d4.y;
        float t2 = sn + R.d4.z, t3 = sn + R.d4.w;
        float v0 = t0 > 0.f ? t0 : 0.2f * t0;
        float v1 = t1 > 0.f ? t1 : 0.2f * t1;
        float v2 = t2 > 0.f ? t2 : 0.2f * t2;
        float v3 = t3 > 0.f ? t3 : 0.2f * t3;
        float e0 = (R.a4[p].x != 0) ? exp2f((v0 - Mn) * LOG2E) : 0.f;
        float e1 = (R.a4[p].y != 0) ? exp2f((v1 - Mn) * LOG2E) : 0.f;
        float e2 = (R.a4[p].z != 0) ? exp2f((v2 - Mn) * LOG2E) : 0.f;
        float e3 = (R.a4[p].w != 0) ? exp2f((v3 - Mn) * LOG2E) : 0.f;
        Lp[p] += (e0 + e1) + (e2 + e3);
    }
}

template <bool WRITE_ALPHA>
__device__ __forceinline__ void attn_tile_body(
    int mb, AdjD& cur, AdjD& nxt,
    const int* adj_base, const float* dg, int ac4,
    const unsigned short* hbase,
    unsigned short* al_lds, unsigned short* hT_lds,
    const float (&sreg)[8], const float (&Mreg)[8], const float (&Lin)[8],
    float* alpha_base, int ar0, int hrow0, int hbyte,
    int w, int col, int quad, f32x4 (&acc)[8])
{
    // ---- issue ALL VMEM for this iteration up front (phase A covers it) ----
    bf16x8 hv[8];
#pragma unroll
    for (int q = 0; q < 8; ++q)
        hv[q] = *(const bf16x8*)(hbase + (size_t)(q * 16) * NN + mb);
    adjd_load((mb + 128) & (NN - 1), adj_base, dg, ac4, nxt);

    // ---- phase A: alpha (bf16 -> LDS swizzled; fp32 -> coalesced store) ----
#pragma unroll
    for (int p = 0; p < 8; ++p) {
        int row = p * 8 + ar0;
        float sn = sreg[p], Mn = Mreg[p], Li = Lin[p];
        float t0 = sn + cur.d4.x, t1 = sn + cur.d4.y;
        float t2 = sn + cur.d4.z, t3 = sn + cur.d4.w;
        float v0 = t0 > 0.f ? t0 : 0.2f * t0;
        float v1 = t1 > 0.f ? t1 : 0.2f * t1;
        float v2 = t2 > 0.f ? t2 : 0.2f * t2;
        float v3 = t3 > 0.f ? t3 : 0.2f * t3;
        float e0 = (cur.a4[p].x != 0) ? exp2f((v0 - Mn) * LOG2E) * Li : 0.f;
        float e1 = (cur.a4[p].y != 0) ? exp2f((v1 - Mn) * LOG2E) * Li : 0.f;
        float e2 = (cur.a4[p].z != 0) ? exp2f((v2 - Mn) * LOG2E) * Li : 0.f;
        float e3 = (cur.a4[p].w != 0) ? exp2f((v3 - Mn) * LOG2E) * Li : 0.f;
        bf16x4 pk;
        pk[0] = (short)f2bf(e0); pk[1] = (short)f2bf(e1);
        pk[2] = (short)f2bf(e2); pk[3] = (short)f2bf(e3);
        int abyte = (ac4 * 2) ^ ((row & 15) << 4);      // swizzled byte-in-row
        *(bf16x4*)&al_lds[row * 128 + (abyte >> 1)] = pk;
        if (WRITE_ALPHA) {
            float4 ev; ev.x = e0; ev.y = e1; ev.z = e2; ev.w = e3;
            *(float4*)(alpha_base + (size_t)(p * 8) * NN + mb) = ev;
        }
    }
    // ---- phase B: stage hT chunk [128 o][128 m], swizzled ----
#pragma unroll
    for (int q = 0; q < 8; ++q)
        *(bf16x8*)&hT_lds[(q * 16 + hrow0) * 128 + (hbyte >> 1)] = hv[q];

    __syncthreads();
    // ---- phase C: MFMA (swizzled reads; row&15 == col on both tiles) ----
#pragma unroll
    for (int k = 0; k < 4; ++k) {
        int cbyte = (k * 64 + quad * 16) ^ (col << 4);
        bf16x8 af = *(const bf16x8*)&al_lds[(w * 16 + col) * 128 + (cbyte >> 1)];
#pragma unroll
        for (int ot = 0; ot < 8; ++ot) {
            bf16x8 bfv = *(const bf16x8*)&hT_lds[(ot * 16 + col) * 128 + (cbyte >> 1)];
            acc[ot] = __builtin_amdgcn_mfma_f32_16x16x32_bf16(af, bfv, acc[ot], 0, 0, 0);
        }
    }
    __syncthreads();   // MFMA reads done; LDS free for next phase A/B
}

template <bool WRITE_ALPHA>
__global__ __launch_bounds__(256) void k_attn_mfma(const int* __restrict__ adj,
                                                   const float* __restrict__ s_in,
                                                   const float* __restrict__ d_in_,
                                                   const float* __restrict__ dmax_,
                                                   const unsigned short* __restrict__ hT,
                                                   float* __restrict__ out_scr,
                                                   float* __restrict__ alpha_out,
                                                   float* __restrict__ Li_out) {
    __shared__ unsigned short al_lds[64 * 128];    // XOR-swizzled, no pad
    __shared__ unsigned short hT_lds[128 * 128];   // XOR-swizzled, no pad
    int tid = threadIdx.x;
    // XCD-aware bijective swizzle (512 blocks % 8 XCDs == 0).
    int bid = (int)(blockIdx.x & 7) * 64 + (int)(blockIdx.x >> 3);
    int bh = bid >> 5;
    int nb = (bid & 31) * 64;
    int b = bh >> 2;

    // phase-A mapping: 8 passes; pass p: row = p*8 + ar0, float-col = ac4..+3
    int ar0 = tid >> 5;                 // 0..7
    int ac4 = (tid & 31) * 4;           // 0..124
    const int* adj_base = adj + ((size_t)b * NN + nb + ar0) * NN + ac4;
    float* alpha_base = WRITE_ALPHA
        ? alpha_out + ((size_t)bh * NN + nb + ar0) * NN + ac4 : nullptr;
    const float* dg = d_in_ + (size_t)bh * NN;     // L2-hot 8 KB row

    // per-row stabilizer + s (in regs; rows p*8+ar0, shared by 32-lane group)
    float dmx = dmax_[bh];
    float sreg[8], Mreg[8];
#pragma unroll
    for (int p = 0; p < 8; ++p) {
        sreg[p] = s_in[bh * NN + nb + p * 8 + ar0];
        float t = sreg[p] + dmx;
        Mreg[p] = t > 0.f ? t : 0.2f * t;
    }

    // ---------------- pass 1: row sums L (register-resident) ----------------
    float Lp[8];
#pragma unroll
    for (int p = 0; p < 8; ++p) Lp[p] = 0.f;
    {
        AdjD A0, A1;
        adjd_load(0, adj_base, dg, ac4, A0);
        for (int mb = 0; mb < NN; mb += 256) {
            adjd_load(mb + 128, adj_base, dg, ac4, A1);
            p1_accum(A0, sreg, Mreg, Lp);
            adjd_load((mb + 256) & (NN - 1), adj_base, dg, ac4, A0);
            p1_accum(A1, sreg, Mreg, Lp);
        }
    }
    // reduce across the 32 lanes sharing each row (xor stays in 32-halves)
#pragma unroll
    for (int off = 16; off >= 1; off >>= 1)
#pragma unroll
        for (int p = 0; p < 8; ++p)
            Lp[p] += __shfl_xor(Lp[p], off, 64);
    float Lin[8];
#pragma unroll
    for (int p = 0; p < 8; ++p) Lin[p] = Lp[p] > 0.f ? 1.f / Lp[p] : 0.f;
    if (!WRITE_ALPHA && (tid & 31) == 0) {
#pragma unroll
        for (int p = 0; p < 8; ++p)
            Li_out[bh * NN + nb + p * 8 + ar0] = Lin[p];
    }

    // ---------------- pass 2: alpha -> LDS -> MFMA (pipelined) --------------
    // phase-B mapping: 16 lanes x 16B = 256B contiguous per o-row
    int hrow0 = tid >> 4;               // 0..15
    int hcolu = (tid & 15) * 8;         // ushort col 0..120
    const unsigned short* hbase = hT + ((size_t)bh * DD + hrow0) * NN + hcolu;
    int hbyte = (hcolu * 2) ^ (hrow0 << 4);
    // phase-C mapping: wave/lane
    int l = tid & 63, w = tid >> 6, col = l & 15, quad = l >> 4;

    f32x4 acc[8];
#pragma unroll
    for (int ot = 0; ot < 8; ++ot) acc[ot] = (f32x4){0.f, 0.f, 0.f, 0.f};

    AdjD A0, A1;
    adjd_load(0, adj_base, dg, ac4, A0);

    for (int mb = 0; mb < NN; mb += 256) {
        attn_tile_body<WRITE_ALPHA>(mb, A0, A1, adj_base, dg, ac4, hbase,
                                    al_lds, hT_lds, sreg, Mreg, Lin,
                                    alpha_base, ar0, hrow0, hbyte,
                                    w, col, quad, acc);
        attn_tile_body<WRITE_ALPHA>(mb + 128, A1, A0, adj_base, dg, ac4, hbase,
                                    al_lds, hT_lds, sreg, Mreg, Lin,
                                    alpha_base, ar0, hrow0, hbyte,
                                    w, col, quad, acc);
    }
    // epilogue: C/D layout col=lane&15, row=quad*4+reg
#pragma unroll
    for (int ot = 0; ot < 8; ++ot)
#pragma unroll
        for (int r = 0; r < 4; ++r)
            out_scr[((size_t)bh * NN + nb + w * 16 + quad * 4 + r) * DD + ot * 16 + col] =
                acc[ot][r];
}

// ---------------------------------------------------------------------------
// Kernel 4: output[b,n,o] = concat_h(out_scr) @ Wp + bias, fp32 store.
// ---------------------------------------------------------------------------
__global__ __launch_bounds__(256) void k_proj(const float* __restrict__ out_scr,
                                              const float* __restrict__ Wp,
                                              const float* __restrict__ bias,
                                              float* __restrict__ out) {
    __shared__ float cs[16 * 512];
    int tid = threadIdx.x;
    int b  = blockIdx.x / (NN / 16);
    int nb = (blockIdx.x % (NN / 16)) * 16;
    for (int idx = tid; idx < 16 * 512; idx += 256) {
        int r = idx >> 9, c = idx & 511;
        int hh = c >> 7, oo = c & 127;
        cs[idx] = out_scr[((size_t)(b * HH + hh) * NN + nb + r) * DD + oo];
    }
    __syncthreads();
    int o = tid & 63, rg = tid >> 6;        // 4 row-groups x 4 rows
    float bv0 = bias[o], bv1 = bias[o + 64];
    float acc0[4], acc1[4];
#pragma unroll
    for (int j = 0; j < 4; ++j) { acc0[j] = bv0; acc1[j] = bv1; }
    for (int k = 0; k < 512; k += 4) {
        float w00 = Wp[(k + 0) * DD + o], w01 = Wp[(k + 0) * DD + o + 64];
        float w10 = Wp[(k + 1) * DD + o], w11 = Wp[(k + 1) * DD + o + 64];
        float w20 = Wp[(k + 2) * DD + o], w21 = Wp[(k + 2) * DD + o + 64];
        float w30 = Wp[(k + 3) * DD + o], w31 = Wp[(k + 3) * DD + o + 64];
#pragma unroll
        for (int j = 0; j < 4; ++j) {
            float4 cq = *(const float4*)&cs[(rg * 4 + j) * 512 + k];
            acc0[j] += cq.x * w00 + cq.y * w10 + cq.z * w20 + cq.w * w30;
            acc1[j] += cq.x * w01 + cq.y * w11 + cq.z * w21 + cq.w * w31;
        }
    }
#pragma unroll
    for (int j = 0; j < 4; ++j) {
        out[((size_t)b * NN + nb + rg * 4 + j) * DD + o]      = acc0[j];
        out[((size_t)b * NN + nb + rg * 4 + j) * DD + o + 64] = acc1[j];
    }
}

// ---------------------------------------------------------------------------
// Kernel 5 (fallback only, ws too small): final fp32 alpha over scratch.
// ---------------------------------------------------------------------------
__global__ __launch_bounds__(256) void k_alpha(const int* __restrict__ adj,
                                               const float* __restrict__ s_in,
                                               const float* __restrict__ d_in_,
                                               const float* __restrict__ dmax_,
                                               const float* __restrict__ Li_in,
                                               float* __restrict__ alpha_out) {
    int tid = threadIdx.x;
    int b = blockIdx.x / NN, n = blockIdx.x % NN;
    float sv[4], Mv[4], Lv[4];
#pragma unroll
    for (int h = 0; h < 4; ++h) {
        sv[h] = s_in[(b * HH + h) * NN + n];
        float t = sv[h] + dmax_[b * HH + h];
        Mv[h] = t > 0.f ? t : 0.2f * t;
        Lv[h] = Li_in[(b * HH + h) * NN + n];
    }
    const int* arow = adj + ((size_t)b * NN + n) * NN;
    for (int m = tid; m < NN; m += 256) {
        int av = arow[m];
#pragma unroll
        for (int h = 0; h < 4; ++h) {
            float val = 0.f;
            if (av != 0) {
                float t = sv[h] + d_in_[(b * HH + h) * NN + m];
                float v = t > 0.f ? t : 0.2f * t;
                val = exp2f((v - Mv[h]) * LOG2E) * Lv[h];
            }
            alpha_out[((size_t)(b * HH + h) * NN + n) * NN + m] = val;
        }
    }
}

// ---------------------------------------------------------------------------
extern "C" void kernel_launch(void* const* d_in, const int* in_sizes, int n_in,
                              void* d_out, int out_size, void* d_ws, size_t ws_size,
                              hipStream_t stream) {
    const float* x    = (const float*)d_in[0];
    const int*   adj  = (const int*)d_in[1];
    const float* W    = (const float*)d_in[2];
    const float* a    = (const float*)d_in[3];
    const float* Wp   = (const float*)d_in[4];
    const float* bias = (const float*)d_in[5];

    float* out       = (float*)d_out;
    float* alpha_out = out + (size_t)BB * NN * DD;

    // Workspace head: stats + WT16.
    float* ws    = (float*)d_ws;
    float* wsv   = ws;
    float* wdv   = wsv + HH * DD;
    float* s_    = wdv + HH * DD;
    float* d_    = s_ + (size_t)BB * HH * NN;
    float* Li_   = d_ + (size_t)BB * HH * NN;
    float* dmax_ = Li_ + (size_t)BB * HH * NN;
    _Float16* WT16 = (_Float16*)(dmax_ + 16);

    const size_t stats_bytes = (2 * HH * DD + 3 * (size_t)BB * HH * NN + 16) * sizeof(float)
                             + (size_t)HH * DD * DD * sizeof(_Float16);   // +128 KB WT16
    const size_t hT_bytes    = (size_t)BB * HH * NN * DD * sizeof(unsigned short);  // 8.39 MB
    const size_t scr_bytes   = (size_t)BB * HH * NN * DD * sizeof(float);           // 16.8 MB
    const bool fused = ws_size >= stats_bytes + hT_bytes + scr_bytes;

    unsigned short* hT;
    float* out_scr;
    if (fused) {
        hT      = (unsigned short*)((char*)d_ws + stats_bytes);
        out_scr = (float*)((char*)hT + hT_bytes);
    } else {
        hT      = (unsigned short*)alpha_out;
        out_scr = alpha_out + (size_t)BB * HH * NN * DD;
    }

    k_prep<<<HH, 128, 0, stream>>>(W, a, wsv, wdv, WT16);
    k_sd<<<BB * NN / 64, 256, 0, stream>>>(x, wsv, wdv, s_, d_);
    k_h_mfma<<<BB * HH * (NN / 64), 256, 0, stream>>>(x, WT16, hT);
    k_dmax<<<BB * HH, 256, 0, stream>>>(d_, dmax_);
    if (fused) {
        k_attn_mfma<true><<<BB * HH * (NN / 64), 256, 0, stream>>>(adj, s_, d_, dmax_,
                                                                   hT, out_scr, alpha_out, Li_);
        k_proj<<<BB * (NN / 16), 256, 0, stream>>>(out_scr, Wp, bias, out);
    } else {
        k_attn_mfma<false><<<BB * HH * (NN / 64), 256, 0, stream>>>(adj, s_, d_, dmax_,
                                                                    hT, out_scr, alpha_out, Li_);
        k_proj<<<BB * (NN / 16), 256, 0, stream>>>(out_scr, Wp, bias, out);
        k_alpha<<<BB * NN, 256, 0, stream>>>(adj, s_, d_, dmax_, Li_, alpha_out);
    }
}